// Round 1
// baseline (338.274 us; speedup 1.0000x reference)
//
#include <hip/hip_runtime.h>
#include <math.h>

#define Bn 64
#define Cn 64
#define Sn 128
#define Hn 512
#define Dn 65536
#define SSn 16384

__device__ __forceinline__ float wred(float v) {
#pragma unroll
    for (int o = 32; o > 0; o >>= 1) v += __shfl_down(v, o, 64);
    return v;
}

// --- row squared norms: x2[b] = sum(x[b]^2), w2[c] = sum(w[c]^2) ---------
__global__ __launch_bounds__(256) void rownorm_k(const float* __restrict__ x,
                                                 const float* __restrict__ w,
                                                 float* __restrict__ x2,
                                                 float* __restrict__ w2) {
    int mat = blockIdx.x;  // 0..127
    const float* src = (mat < Bn) ? (x + (size_t)mat * Dn) : (w + (size_t)(mat - Bn) * Dn);
    float s = 0.f;
    for (int k = threadIdx.x * 4; k < Dn; k += 1024) {
        float4 v = *(const float4*)(src + k);
        s += v.x * v.x + v.y * v.y + v.z * v.z + v.w * v.w;
    }
    s = wred(s);
    __shared__ float red[4];
    if ((threadIdx.x & 63) == 0) red[threadIdx.x >> 6] = s;
    __syncthreads();
    if (threadIdx.x == 0) {
        float t = red[0] + red[1] + red[2] + red[3];
        if (mat < Bn) x2[mat] = t; else w2[mat - Bn] = t;
    }
}

// --- split-K 64x64 dot-product GEMM: acc[i][j] += dot(A[i], B[bidx?bidx[j]:j]) over K-chunk
// fp32 chunk partial -> atomicAdd into double accumulator (accuracy for argmax).
__global__ __launch_bounds__(256) void dots_k(const float* __restrict__ A,
                                              const float* __restrict__ Bm,
                                              const int* __restrict__ bidx,
                                              int K, double* __restrict__ acc) {
    __shared__ float la[64][129];
    __shared__ float lb[64][129];
    const int k0 = blockIdx.x * 128;
    const int tid = threadIdx.x;
    const int lr = tid >> 5;         // 0..7
    const int lc = (tid & 31) * 4;   // 0..124
    for (int r = lr; r < 64; r += 8) {
        float4 va = *(const float4*)(A + (size_t)r * K + k0 + lc);
        la[r][lc] = va.x; la[r][lc + 1] = va.y; la[r][lc + 2] = va.z; la[r][lc + 3] = va.w;
        int br = bidx ? bidx[r] : r;
        float4 vb = *(const float4*)(Bm + (size_t)br * K + k0 + lc);
        lb[r][lc] = vb.x; lb[r][lc + 1] = vb.y; lb[r][lc + 2] = vb.z; lb[r][lc + 3] = vb.w;
    }
    __syncthreads();
    const int ty = tid >> 4, tx = tid & 15;
    float a[4], b[4];
    float accv[4][4] = {};
    for (int k = 0; k < 128; ++k) {
#pragma unroll
        for (int i = 0; i < 4; ++i) a[i] = la[4 * ty + i][k];
#pragma unroll
        for (int j = 0; j < 4; ++j) b[j] = lb[4 * tx + j][k];
#pragma unroll
        for (int i = 0; i < 4; ++i)
#pragma unroll
            for (int j = 0; j < 4; ++j) accv[i][j] += a[i] * b[j];
    }
#pragma unroll
    for (int i = 0; i < 4; ++i)
#pragma unroll
        for (int j = 0; j < 4; ++j)
            atomicAdd(&acc[(size_t)(4 * ty + i) * 64 + 4 * tx + j], (double)accv[i][j]);
}

// --- gram: G = X @ X^T for matrix mat (128x512), block computes 64 rows ---
__global__ __launch_bounds__(256) void gram_k(const float* __restrict__ x,
                                              const float* __restrict__ w,
                                              float* __restrict__ gx,
                                              float* __restrict__ gy) {
    __shared__ float lx[128][129];
    const int mat = blockIdx.x >> 1;          // 0..127
    const int r0 = (blockIdx.x & 1) * 64;     // output row half
    const float* src = (mat < Bn) ? (x + (size_t)mat * Dn) : (w + (size_t)(mat - Bn) * Dn);
    float* dst = (mat < Bn) ? (gx + (size_t)mat * SSn) : (gy + (size_t)(mat - Bn) * SSn);
    const int tid = threadIdx.x;
    const int lr = tid >> 5;          // 0..7
    const int lc = (tid & 31) * 4;    // 0..124
    const int ty = tid >> 4, tx = tid & 15;
    float a[4], bb[8];
    float acc[4][8] = {};
    for (int k0 = 0; k0 < Hn; k0 += 128) {
        __syncthreads();
        for (int r = lr; r < 128; r += 8) {
            float4 v = *(const float4*)(src + (size_t)r * Hn + k0 + lc);
            lx[r][lc] = v.x; lx[r][lc + 1] = v.y; lx[r][lc + 2] = v.z; lx[r][lc + 3] = v.w;
        }
        __syncthreads();
        for (int k = 0; k < 128; ++k) {
#pragma unroll
            for (int i = 0; i < 4; ++i) a[i] = lx[r0 + 4 * ty + i][k];
#pragma unroll
            for (int j = 0; j < 8; ++j) bb[j] = lx[8 * tx + j][k];
#pragma unroll
            for (int i = 0; i < 4; ++i)
#pragma unroll
                for (int j = 0; j < 8; ++j) acc[i][j] += a[i] * bb[j];
        }
    }
#pragma unroll
    for (int i = 0; i < 4; ++i) {
        float* p = dst + (size_t)(r0 + 4 * ty + i) * Sn + 8 * tx;
        *(float4*)p = make_float4(acc[i][0], acc[i][1], acc[i][2], acc[i][3]);
        *(float4*)(p + 4) = make_float4(acc[i][4], acc[i][5], acc[i][6], acc[i][7]);
    }
}

// --- centering in-place + sum of squares: cg = g - rm[s] - cm[t] + gm -----
__global__ __launch_bounds__(256) void center_k(float* __restrict__ gx, float* __restrict__ gy,
                                                float* __restrict__ hxx, float* __restrict__ hyy) {
    __shared__ float lg[128][128];
    __shared__ float rowm[128], colm[128];
    __shared__ float gms;
    __shared__ float red[4];
    const int mat = blockIdx.x;  // 0..127
    float* g = (mat < Bn) ? (gx + (size_t)mat * SSn) : (gy + (size_t)(mat - Bn) * SSn);
    const int tid = threadIdx.x;
    float* lgf = &lg[0][0];
    for (int e = tid * 4; e < SSn; e += 1024)
        *(float4*)(lgf + e) = *(const float4*)(g + e);
    __syncthreads();
    if (tid < 128) {
        float cs = 0.f;
        for (int r = 0; r < 128; ++r) cs += lg[r][tid];      // mean over s (axis -2)
        colm[tid] = cs * (1.f / 128.f);
        float rs = 0.f;
        for (int t = 0; t < 128; ++t) rs += lg[tid][(t + tid) & 127];  // rotated: conflict-free
        rowm[tid] = rs * (1.f / 128.f);
    }
    __syncthreads();
    if (tid == 0) {
        float s = 0.f;
        for (int t = 0; t < 128; ++t) s += colm[t];
        gms = s * (1.f / 128.f);
    }
    __syncthreads();
    const float gm = gms;
    float sq = 0.f;
    for (int e = tid * 4; e < SSn; e += 1024) {
        int s = e >> 7, t = e & 127;
        float4 v = *(float4*)(lgf + e);
        float c0 = v.x - rowm[s] - colm[t] + gm;
        float c1 = v.y - rowm[s] - colm[t + 1] + gm;
        float c2 = v.z - rowm[s] - colm[t + 2] + gm;
        float c3 = v.w - rowm[s] - colm[t + 3] + gm;
        sq += c0 * c0 + c1 * c1 + c2 * c2 + c3 * c3;
        *(float4*)(g + e) = make_float4(c0, c1, c2, c3);
    }
    sq = wred(sq);
    if ((tid & 63) == 0) red[tid >> 6] = sq;
    __syncthreads();
    if (tid == 0) {
        float t = red[0] + red[1] + red[2] + red[3];
        if (mat < Bn) hxx[mat] = t; else hyy[mat - Bn] = t;
    }
}

// --- dist = sqrt(max(x2 + w2 - 2*dot, 0)) ---------------------------------
__global__ __launch_bounds__(256) void dist_k(const double* __restrict__ dots,
                                              const float* __restrict__ x2,
                                              const float* __restrict__ w2,
                                              float* __restrict__ od) {
    int i = blockIdx.x * 256 + threadIdx.x;  // 0..4095
    int b = i >> 6, c = i & 63;
    float d2 = x2[b] + w2[c] - 2.f * (float)dots[i];
    od[i] = sqrtf(fmaxf(d2, 0.f));
}

// --- cka_mat + per-row argmax (first max, matching jnp.argmax) ------------
__global__ void cka_argmax_k(const double* __restrict__ hxy, const float* __restrict__ hxx,
                             const float* __restrict__ hyy, int* __restrict__ idx_i,
                             float* __restrict__ oidx) {
    int b = threadIdx.x;  // 64 threads
    double sx = sqrt((double)hxx[b]);
    double best = -1e300; int bi = 0;
    for (int c = 0; c < Cn; ++c) {
        double r = fabs(hxy[b * Cn + c]) / (sx * sqrt((double)hyy[c]));
        double v = -log(r + 1e-8);
        if (v > best) { best = v; bi = c; }
    }
    idx_i[b] = bi;
    oidx[b] = (float)bi;
}

// --- final loss: -log(mean(|hxy2|/(sqrt(hxx) sqrt(hyy[idx]))) + eps) ------
__global__ __launch_bounds__(256) void loss_k(const double* __restrict__ hxy2,
                                              const float* __restrict__ hxx,
                                              const float* __restrict__ hyy,
                                              const int* __restrict__ idx_i,
                                              float* __restrict__ out0) {
    double s = 0.0;
    for (int e = threadIdx.x; e < 4096; e += 256) {
        int b = e >> 6, c = e & 63;
        s += fabs(hxy2[e]) / (sqrt((double)hxx[b]) * sqrt((double)hyy[idx_i[c]]));
    }
#pragma unroll
    for (int o = 32; o > 0; o >>= 1) s += __shfl_down(s, o, 64);
    __shared__ double red[4];
    if ((threadIdx.x & 63) == 0) red[threadIdx.x >> 6] = s;
    __syncthreads();
    if (threadIdx.x == 0) {
        double t = red[0] + red[1] + red[2] + red[3];
        out0[0] = (float)(-log(t / 4096.0 + 1e-8));
    }
}

extern "C" void kernel_launch(void* const* d_in, const int* in_sizes, int n_in,
                              void* d_out, int out_size, void* d_ws, size_t ws_size,
                              hipStream_t stream) {
    const float* x = (const float*)d_in[0];   // (64, 65536)
    const float* w = (const float*)d_in[1];   // (64, 65536)
    float* out = (float*)d_out;
    // out layout: [0]=loss, [1..4096]=dist, [4097..4198400]=centroid copy, [4198401..4198464]=idx
    // Scratch lives inside the centroid-copy region and is overwritten by the final memcpy:
    float* cgx = out + 8192;                       // 64*16384 floats
    float* cgy = cgx + (size_t)Bn * SSn;           // 64*16384 floats
    double* dd = (double*)(out + 2105344);         // 8-byte aligned
    double* dots = dd;                             // 4096 doubles
    double* hxy  = dd + 4096;                      // 4096
    double* hxy2 = dd + 8192;                      // 4096
    float* wf  = out + 2129920;
    float* x2  = wf;
    float* w2  = wf + 64;
    float* hxx = wf + 128;
    float* hyy = wf + 192;
    int* idx_i = (int*)(wf + 256);

    hipMemsetAsync(dd, 0, 12288 * sizeof(double), stream);
    rownorm_k<<<128, 256, 0, stream>>>(x, w, x2, w2);
    dots_k<<<Dn / 128, 256, 0, stream>>>(x, w, nullptr, Dn, dots);
    dist_k<<<16, 256, 0, stream>>>(dots, x2, w2, out + 1);
    gram_k<<<256, 256, 0, stream>>>(x, w, cgx, cgy);
    center_k<<<128, 256, 0, stream>>>(cgx, cgy, hxx, hyy);
    dots_k<<<SSn / 128, 256, 0, stream>>>(cgx, cgy, nullptr, SSn, hxy);
    cka_argmax_k<<<1, 64, 0, stream>>>(hxy, hxx, hyy, idx_i, out + 4198401);
    dots_k<<<SSn / 128, 256, 0, stream>>>(cgx, cgy, idx_i, SSn, hxy2);
    loss_k<<<1, 256, 0, stream>>>(hxy2, hxx, hyy, idx_i, out);
    hipMemcpyAsync(out + 4097, w, (size_t)Cn * Dn * sizeof(float),
                   hipMemcpyDeviceToDevice, stream);
}

// Round 2
// 299.347 us; speedup vs baseline: 1.1300x; 1.1300x over previous
//
#include <hip/hip_runtime.h>
#include <math.h>

#define Bn 64
#define Cn 64
#define Sn 128
#define Hn 512
#define Dn 65536
#define SSn 16384
#define PAD 132

__device__ __forceinline__ float wredf(float v) {
#pragma unroll
    for (int o = 32; o > 0; o >>= 1) v += __shfl_down(v, o, 64);
    return v;
}

// --- gram: G = X @ X^T for matrix mat (128x512) -> (128x128); 2 blocks/mat --
__global__ __launch_bounds__(256) void gram_k(const float* __restrict__ x,
                                              const float* __restrict__ w,
                                              float* __restrict__ gx,
                                              float* __restrict__ gy) {
    __shared__ float lx[128][PAD];
    const int mat = blockIdx.x >> 1;          // 0..127
    const int r0 = (blockIdx.x & 1) * 64;     // output row half
    const float* src = (mat < Bn) ? (x + (size_t)mat * Dn) : (w + (size_t)(mat - Bn) * Dn);
    float* dst = (mat < Bn) ? (gx + (size_t)mat * SSn) : (gy + (size_t)(mat - Bn) * SSn);
    const int tid = threadIdx.x;
    const int lr = tid >> 5, lc = (tid & 31) * 4;
    const int ty = tid >> 4, tx = tid & 15;
    float acc[4][8] = {};
    for (int k0 = 0; k0 < Hn; k0 += 128) {
        __syncthreads();
        for (int r = lr; r < 128; r += 8)
            *(float4*)&lx[r][lc] = *(const float4*)(src + (size_t)r * Hn + k0 + lc);
        __syncthreads();
        for (int k = 0; k < 128; k += 4) {
            float4 av[4], bv[8];
#pragma unroll
            for (int i = 0; i < 4; ++i) av[i] = *(const float4*)&lx[r0 + 4 * ty + i][k];
#pragma unroll
            for (int j = 0; j < 8; ++j) bv[j] = *(const float4*)&lx[16 * j + tx][k];
#pragma unroll
            for (int i = 0; i < 4; ++i)
#pragma unroll
                for (int j = 0; j < 8; ++j)
                    acc[i][j] += av[i].x * bv[j].x + av[i].y * bv[j].y +
                                 av[i].z * bv[j].z + av[i].w * bv[j].w;
        }
    }
#pragma unroll
    for (int i = 0; i < 4; ++i)
#pragma unroll
        for (int j = 0; j < 8; ++j)
            dst[(size_t)(r0 + 4 * ty + i) * Sn + 16 * j + tx] = acc[i][j];
}

// --- x2[b]=trace(gram_x[b]), w2[c]=trace(gram_w[c]) (uncentered grams) ----
__global__ void trace_k(const float* __restrict__ gx, const float* __restrict__ gy,
                        float* __restrict__ x2, float* __restrict__ w2) {
    const int mat = blockIdx.x;  // 0..127, 128 threads
    const float* g = (mat < Bn) ? (gx + (size_t)mat * SSn) : (gy + (size_t)(mat - Bn) * SSn);
    const int tid = threadIdx.x;
    float v = g[(size_t)tid * 129];  // diagonal
    v = wredf(v);
    __shared__ float r2[2];
    if ((tid & 63) == 0) r2[tid >> 6] = v;
    __syncthreads();
    if (tid == 0) {
        float t = r2[0] + r2[1];
        if (mat < Bn) x2[mat] = t; else w2[mat - Bn] = t;
    }
}

// --- split-K 64x64 dots: per-block fp32 partials (no atomics) -------------
template <int CPB>
__global__ __launch_bounds__(256) void dotsp_k(const float* __restrict__ A,
                                               const float* __restrict__ Bm,
                                               int K, float* __restrict__ partials) {
    __shared__ float la[64][PAD];
    __shared__ float lb[64][PAD];
    const int tid = threadIdx.x;
    const int lr = tid >> 5, lc = (tid & 31) * 4;
    const int ty = tid >> 4, tx = tid & 15;
    float acc[4][4] = {};
    for (int c = 0; c < CPB; ++c) {
        const int k0 = (blockIdx.x * CPB + c) * 128;
        __syncthreads();
        for (int r = lr; r < 64; r += 8) {
            *(float4*)&la[r][lc] = *(const float4*)(A + (size_t)r * K + k0 + lc);
            *(float4*)&lb[r][lc] = *(const float4*)(Bm + (size_t)r * K + k0 + lc);
        }
        __syncthreads();
        for (int k = 0; k < 128; k += 4) {
            float4 av[4], bv[4];
#pragma unroll
            for (int i = 0; i < 4; ++i) av[i] = *(const float4*)&la[4 * ty + i][k];
#pragma unroll
            for (int j = 0; j < 4; ++j) bv[j] = *(const float4*)&lb[16 * j + tx][k];
#pragma unroll
            for (int i = 0; i < 4; ++i)
#pragma unroll
                for (int j = 0; j < 4; ++j)
                    acc[i][j] += av[i].x * bv[j].x + av[i].y * bv[j].y +
                                 av[i].z * bv[j].z + av[i].w * bv[j].w;
        }
        __syncthreads();
    }
    float* p = partials + (size_t)blockIdx.x * 4096;
#pragma unroll
    for (int i = 0; i < 4; ++i)
#pragma unroll
        for (int j = 0; j < 4; ++j)
            p[(4 * ty + i) * 64 + 16 * j + tx] = acc[i][j];
}

// --- deterministic double reduce of partials -> dist output ----------------
__global__ __launch_bounds__(256) void reduce_dist_k(const float* __restrict__ partials, int P,
                                                     const float* __restrict__ x2,
                                                     const float* __restrict__ w2,
                                                     float* __restrict__ od) {
    const int i = blockIdx.x * 256 + threadIdx.x;  // 0..4095
    double s = 0.0;
    for (int p = 0; p < P; ++p) s += (double)partials[(size_t)p * 4096 + i];
    const int b = i >> 6, c = i & 63;
    float d2 = x2[b] + w2[c] - 2.f * (float)s;
    od[i] = sqrtf(fmaxf(d2, 0.f));
}

// --- deterministic double reduce of partials -> hxy ------------------------
__global__ __launch_bounds__(256) void reduce_hxy_k(const float* __restrict__ partials, int P,
                                                    double* __restrict__ hxy) {
    const int i = blockIdx.x * 256 + threadIdx.x;
    double s = 0.0;
    for (int p = 0; p < P; ++p) s += (double)partials[(size_t)p * 4096 + i];
    hxy[i] = s;
}

// --- centering in-place + sum of squares ----------------------------------
__global__ __launch_bounds__(256) void center_k(float* __restrict__ gx, float* __restrict__ gy,
                                                float* __restrict__ hxx, float* __restrict__ hyy) {
    __shared__ float lg[128][128];
    __shared__ float rowm[128], colm[128];
    __shared__ float gms;
    __shared__ float red[4];
    const int mat = blockIdx.x;  // 0..127
    float* g = (mat < Bn) ? (gx + (size_t)mat * SSn) : (gy + (size_t)(mat - Bn) * SSn);
    const int tid = threadIdx.x;
    float* lgf = &lg[0][0];
    for (int e = tid * 4; e < SSn; e += 1024)
        *(float4*)(lgf + e) = *(const float4*)(g + e);
    __syncthreads();
    if (tid < 128) {
        float cs = 0.f;
        for (int r = 0; r < 128; ++r) cs += lg[r][tid];
        colm[tid] = cs * (1.f / 128.f);
        float rs = 0.f;
        for (int t = 0; t < 128; ++t) rs += lg[tid][(t + tid) & 127];  // rotated: conflict-free
        rowm[tid] = rs * (1.f / 128.f);
    }
    __syncthreads();
    if (tid == 0) {
        float s = 0.f;
        for (int t = 0; t < 128; ++t) s += colm[t];
        gms = s * (1.f / 128.f);
    }
    __syncthreads();
    const float gm = gms;
    float sq = 0.f;
    for (int e = tid * 4; e < SSn; e += 1024) {
        int s = e >> 7, t = e & 127;
        float4 v = *(float4*)(lgf + e);
        float c0 = v.x - rowm[s] - colm[t] + gm;
        float c1 = v.y - rowm[s] - colm[t + 1] + gm;
        float c2 = v.z - rowm[s] - colm[t + 2] + gm;
        float c3 = v.w - rowm[s] - colm[t + 3] + gm;
        sq += c0 * c0 + c1 * c1 + c2 * c2 + c3 * c3;
        *(float4*)(g + e) = make_float4(c0, c1, c2, c3);
    }
    sq = wredf(sq);
    if ((tid & 63) == 0) red[tid >> 6] = sq;
    __syncthreads();
    if (tid == 0) {
        float t = red[0] + red[1] + red[2] + red[3];
        if (mat < Bn) hxx[mat] = t; else hyy[mat - Bn] = t;
    }
}

// --- fused: cka argmax per row, then loss via hxy2[b][c] = hxy[b][idx[c]] --
__global__ void finalize_k(const double* __restrict__ hxy, const float* __restrict__ hxx,
                           const float* __restrict__ hyy, float* __restrict__ out0,
                           float* __restrict__ oidx) {
    __shared__ int sidx[64];
    __shared__ double sred[4];
    const int tid = threadIdx.x;  // 256
    if (tid < 64) {
        const int b = tid;
        double sx = sqrt((double)hxx[b]);
        double best = -1e300; int bi = 0;
        for (int c = 0; c < Cn; ++c) {
            double r = fabs(hxy[b * Cn + c]) / (sx * sqrt((double)hyy[c]));
            double v = -log(r + 1e-8);
            if (v > best) { best = v; bi = c; }
        }
        sidx[b] = bi;
        oidx[b] = (float)bi;
    }
    __syncthreads();
    double s = 0.0;
    for (int e = tid; e < 4096; e += 256) {
        const int b = e >> 6, c = e & 63;
        const int ic = sidx[c];
        s += fabs(hxy[b * Cn + ic]) / (sqrt((double)hxx[b]) * sqrt((double)hyy[ic]));
    }
#pragma unroll
    for (int o = 32; o > 0; o >>= 1) s += __shfl_down(s, o, 64);
    if ((tid & 63) == 0) sred[tid >> 6] = s;
    __syncthreads();
    if (tid == 0) {
        double t = sred[0] + sred[1] + sred[2] + sred[3];
        out0[0] = (float)(-log(t / 4096.0 + 1e-8));
    }
}

extern "C" void kernel_launch(void* const* d_in, const int* in_sizes, int n_in,
                              void* d_out, int out_size, void* d_ws, size_t ws_size,
                              hipStream_t stream) {
    const float* x = (const float*)d_in[0];   // (64, 65536)
    const float* w = (const float*)d_in[1];   // (64, 65536)
    float* out = (float*)d_out;
    // out layout: [0]=loss, [1..4096]=dist, [4097..4198400]=centroid copy, [4198401..]=idx
    // All scratch lives inside the centroid-copy region; final memcpy overwrites it.
    float* cgx = out + 8192;                        // 64*16384
    float* cgy = cgx + (size_t)Bn * SSn;            // 64*16384
    double* hxyD = (double*)(out + 2105344);        // 4096 doubles (8B aligned)
    float* partials = out + 2113536;                // up to 256*4096 floats
    float* wf = out + 3162112;
    float* x2  = wf;
    float* w2  = wf + 64;
    float* hxx = wf + 128;
    float* hyy = wf + 192;

    gram_k<<<256, 256, 0, stream>>>(x, w, cgx, cgy);
    trace_k<<<128, 128, 0, stream>>>(cgx, cgy, x2, w2);
    dotsp_k<2><<<256, 256, 0, stream>>>(x, w, Dn, partials);
    reduce_dist_k<<<16, 256, 0, stream>>>(partials, 256, x2, w2, out + 1);
    center_k<<<128, 256, 0, stream>>>(cgx, cgy, hxx, hyy);
    dotsp_k<1><<<128, 256, 0, stream>>>(cgx, cgy, SSn, partials);
    reduce_hxy_k<<<16, 256, 0, stream>>>(partials, 128, hxyD);
    finalize_k<<<1, 256, 0, stream>>>(hxyD, hxx, hyy, out, out + 4198401);
    hipMemcpyAsync(out + 4097, w, (size_t)Cn * Dn * sizeof(float),
                   hipMemcpyDeviceToDevice, stream);
}

// Round 3
// 249.825 us; speedup vs baseline: 1.3540x; 1.1982x over previous
//
#include <hip/hip_runtime.h>
#include <math.h>

#define Bn 64
#define Cn 64
#define Sn 128
#define Hn 512
#define Dn 65536
#define SSn 16384

__device__ __forceinline__ float wredf(float v) {
#pragma unroll
    for (int o = 32; o > 0; o >>= 1) v += __shfl_down(v, o, 64);
    return v;
}

// --- gram (128x512 -> 128x128) + fused row-sums + fused trace --------------
// grid 512 = 4 blocks/mat (32 out rows each); 128 threads; Kc=64; 2 blocks/CU
__global__ __launch_bounds__(128) void gram_k(const float* __restrict__ x,
                                              const float* __restrict__ w,
                                              float* __restrict__ gx,
                                              float* __restrict__ gy,
                                              float* __restrict__ gsum,
                                              float* __restrict__ x2,
                                              float* __restrict__ w2) {
    __shared__ float lx[128][68];
    const int mat = blockIdx.x >> 2;          // 0..127
    const int r0 = (blockIdx.x & 3) * 32;     // output row quarter
    const float* src = (mat < Bn) ? (x + (size_t)mat * Dn) : (w + (size_t)(mat - Bn) * Dn);
    float* dst = (mat < Bn) ? (gx + (size_t)mat * SSn) : (gy + (size_t)(mat - Bn) * SSn);
    const int tid = threadIdx.x;
    const int sr = tid >> 4;          // staging row 0..7
    const int lc = (tid & 15) * 4;    // staging col 0..60
    const int ry = tid >> 4;          // 0..7
    const int tx = tid & 15;
    float acc[4][8] = {};
    float ssq = 0.f;
    for (int k0 = 0; k0 < Hn; k0 += 64) {
        __syncthreads();
        for (int r = sr; r < 128; r += 8) {
            float4 v = *(const float4*)(src + (size_t)r * Hn + k0 + lc);
            *(float4*)&lx[r][lc] = v;
            if (r0 == 0) ssq += v.x * v.x + v.y * v.y + v.z * v.z + v.w * v.w;
        }
        __syncthreads();
        for (int k = 0; k < 64; k += 4) {
            float4 av[4], bv[8];
#pragma unroll
            for (int i = 0; i < 4; ++i) av[i] = *(const float4*)&lx[r0 + 4 * ry + i][k];
#pragma unroll
            for (int j = 0; j < 8; ++j) bv[j] = *(const float4*)&lx[16 * j + tx][k];
#pragma unroll
            for (int i = 0; i < 4; ++i)
#pragma unroll
                for (int j = 0; j < 8; ++j)
                    acc[i][j] += av[i].x * bv[j].x + av[i].y * bv[j].y +
                                 av[i].z * bv[j].z + av[i].w * bv[j].w;
        }
    }
#pragma unroll
    for (int i = 0; i < 4; ++i)
#pragma unroll
        for (int j = 0; j < 8; ++j)
            dst[(size_t)(r0 + 4 * ry + i) * Sn + 16 * j + tx] = acc[i][j];
    // row sums (gram symmetric => row sums == col sums)
#pragma unroll
    for (int i = 0; i < 4; ++i) {
        float rs = acc[i][0] + acc[i][1] + acc[i][2] + acc[i][3] +
                   acc[i][4] + acc[i][5] + acc[i][6] + acc[i][7];
#pragma unroll
        for (int m = 1; m < 16; m <<= 1) rs += __shfl_xor(rs, m, 64);
        if (tx == 0) gsum[mat * Sn + r0 + 4 * ry + i] = rs;
    }
    // trace == sum of squares of src, accumulated during staging (r0==0 only)
    if (r0 == 0) {
        ssq = wredf(ssq);
        __shared__ float sp[2];
        if ((tid & 63) == 0) sp[tid >> 6] = ssq;
        __syncthreads();
        if (tid == 0) {
            float t = sp[0] + sp[1];
            if (mat < Bn) x2[mat] = t; else w2[mat - Bn] = t;
        }
    }
}

// --- streaming centering: c = g - rm[s] - rm[t] + gm; hxx/hyy --------------
__global__ __launch_bounds__(256) void center_k(float* __restrict__ gx, float* __restrict__ gy,
                                                const float* __restrict__ gsum,
                                                float* __restrict__ hxx, float* __restrict__ hyy) {
    __shared__ float rm[128];
    __shared__ float gmv;
    __shared__ float red[4];
    const int mat = blockIdx.x;  // 0..127
    float* g = (mat < Bn) ? (gx + (size_t)mat * SSn) : (gy + (size_t)(mat - Bn) * SSn);
    const int tid = threadIdx.x;
    float rsv = 0.f;
    if (tid < 128) {
        rsv = gsum[mat * Sn + tid];
        rm[tid] = rsv * (1.f / 128.f);
    }
    float gs = wredf(rsv);
    if ((tid & 63) == 0) red[tid >> 6] = gs;
    __syncthreads();
    if (tid == 0) gmv = (red[0] + red[1]) * (1.f / (128.f * 128.f));
    __syncthreads();
    const float gm = gmv;
    const int t4 = (4 * tid) & 127;            // fixed col base per thread
    const float4 rmt = *(const float4*)&rm[t4];
    float sq = 0.f;
    for (int p = 0; p < 16; ++p) {
        const int idx4 = tid + 256 * p;
        const int s = idx4 >> 5;
        const float rms = rm[s] - gm;          // combined
        float4 v = *(float4*)(g + 4 * idx4);
        float c0 = v.x - rms - rmt.x;
        float c1 = v.y - rms - rmt.y;
        float c2 = v.z - rms - rmt.z;
        float c3 = v.w - rms - rmt.w;
        sq += c0 * c0 + c1 * c1 + c2 * c2 + c3 * c3;
        *(float4*)(g + 4 * idx4) = make_float4(c0, c1, c2, c3);
    }
    sq = wredf(sq);
    if ((tid & 63) == 0) red[tid >> 6] = sq;
    __syncthreads();
    if (tid == 0) {
        float t = red[0] + red[1] + red[2] + red[3];
        if (mat < Bn) hxx[mat] = t; else hyy[mat - Bn] = t;
    }
}

// --- split-K 64x64 dots: per-block fp32 partials ---------------------------
// 256 threads, 4x4 per thread; grid = K/(KC*CPB) = 256 blocks
template <int KC, int CPB>
__global__ __launch_bounds__(256) void dotsp_k(const float* __restrict__ A,
                                               const float* __restrict__ Bm,
                                               int K, float* __restrict__ partials) {
    __shared__ float la[64][KC + 4];
    __shared__ float lb[64][KC + 4];
    const int tid = threadIdx.x;
    const int NC4 = KC / 4;                    // float4s per row
    const int slc = (tid & (NC4 - 1)) * 4;
    const int sr0 = tid / NC4;
    const int srstep = 256 / NC4;
    const int ry = tid >> 4;                   // 0..15
    const int tx = tid & 15;
    float acc[4][4] = {};
    for (int c = 0; c < CPB; ++c) {
        const int k0 = (blockIdx.x * CPB + c) * KC;
        __syncthreads();
        for (int r = sr0; r < 64; r += srstep) {
            *(float4*)&la[r][slc] = *(const float4*)(A + (size_t)r * K + k0 + slc);
            *(float4*)&lb[r][slc] = *(const float4*)(Bm + (size_t)r * K + k0 + slc);
        }
        __syncthreads();
        for (int k = 0; k < KC; k += 4) {
            float4 av[4], bv[4];
#pragma unroll
            for (int i = 0; i < 4; ++i) av[i] = *(const float4*)&la[4 * ry + i][k];
#pragma unroll
            for (int j = 0; j < 4; ++j) bv[j] = *(const float4*)&lb[16 * j + tx][k];
#pragma unroll
            for (int i = 0; i < 4; ++i)
#pragma unroll
                for (int j = 0; j < 4; ++j)
                    acc[i][j] += av[i].x * bv[j].x + av[i].y * bv[j].y +
                                 av[i].z * bv[j].z + av[i].w * bv[j].w;
        }
    }
    float* p = partials + (size_t)blockIdx.x * 4096;
#pragma unroll
    for (int i = 0; i < 4; ++i)
#pragma unroll
        for (int j = 0; j < 4; ++j)
            p[(4 * ry + i) * 64 + 16 * j + tx] = acc[i][j];
}

// --- deterministic double reduce -> dist -----------------------------------
__global__ __launch_bounds__(64) void reduce_dist_k(const float* __restrict__ partials,
                                                    const float* __restrict__ x2,
                                                    const float* __restrict__ w2,
                                                    float* __restrict__ od) {
    const int i = blockIdx.x * 64 + threadIdx.x;  // 0..4095
    double s = 0.0;
    for (int p = 0; p < 256; ++p) s += (double)partials[(size_t)p * 4096 + i];
    const int b = i >> 6, c = i & 63;
    float d2 = x2[b] + w2[c] - 2.f * (float)s;
    od[i] = sqrtf(fmaxf(d2, 0.f));
}

// --- deterministic double reduce -> hxy ------------------------------------
__global__ __launch_bounds__(64) void reduce_hxy_k(const float* __restrict__ partials,
                                                   double* __restrict__ hxy) {
    const int i = blockIdx.x * 64 + threadIdx.x;
    double s = 0.0;
    for (int p = 0; p < 256; ++p) s += (double)partials[(size_t)p * 4096 + i];
    hxy[i] = s;
}

// --- fused: cka argmax per row, then loss via hxy2[b][c] = hxy[b][idx[c]] --
__global__ void finalize_k(const double* __restrict__ hxy, const float* __restrict__ hxx,
                           const float* __restrict__ hyy, float* __restrict__ out0,
                           float* __restrict__ oidx) {
    __shared__ int sidx[64];
    __shared__ double sred[4];
    const int tid = threadIdx.x;  // 256
    if (tid < 64) {
        const int b = tid;
        double sx = sqrt((double)hxx[b]);
        double best = -1e300; int bi = 0;
        for (int c = 0; c < Cn; ++c) {
            double r = fabs(hxy[b * Cn + c]) / (sx * sqrt((double)hyy[c]));
            double v = -log(r + 1e-8);
            if (v > best) { best = v; bi = c; }
        }
        sidx[b] = bi;
        oidx[b] = (float)bi;
    }
    __syncthreads();
    double s = 0.0;
    for (int e = tid; e < 4096; e += 256) {
        const int b = e >> 6, c = e & 63;
        const int ic = sidx[c];
        s += fabs(hxy[b * Cn + ic]) / (sqrt((double)hxx[b]) * sqrt((double)hyy[ic]));
    }
#pragma unroll
    for (int o = 32; o > 0; o >>= 1) s += __shfl_down(s, o, 64);
    if ((tid & 63) == 0) sred[tid >> 6] = s;
    __syncthreads();
    if (tid == 0) {
        double t = sred[0] + sred[1] + sred[2] + sred[3];
        out0[0] = (float)(-log(t / 4096.0 + 1e-8));
    }
}

extern "C" void kernel_launch(void* const* d_in, const int* in_sizes, int n_in,
                              void* d_out, int out_size, void* d_ws, size_t ws_size,
                              hipStream_t stream) {
    const float* x = (const float*)d_in[0];   // (64, 65536)
    const float* w = (const float*)d_in[1];   // (64, 65536)
    float* out = (float*)d_out;
    // out layout: [0]=loss, [1..4096]=dist, [4097..4198400]=centroid copy, [4198401..]=idx
    // All scratch lives inside the centroid-copy region; final memcpy overwrites it.
    float* cgx = out + 8192;                        // 1048576 fl
    float* cgy = out + 1056768;                     // 1048576 fl
    float* partials = out + 2105344;                // 1048576 fl (P=256)
    float* gsum = out + 3153920;                    // 16384 fl
    double* hxyD = (double*)(out + 3170304);        // 4096 dbl (8B aligned)
    float* x2  = out + 3178496;
    float* w2  = x2 + 64;
    float* hxx = x2 + 128;
    float* hyy = x2 + 192;

    gram_k<<<512, 128, 0, stream>>>(x, w, cgx, cgy, gsum, x2, w2);
    dotsp_k<64, 4><<<256, 256, 0, stream>>>(x, w, Dn, partials);
    reduce_dist_k<<<64, 64, 0, stream>>>(partials, x2, w2, out + 1);
    center_k<<<128, 256, 0, stream>>>(cgx, cgy, gsum, hxx, hyy);
    dotsp_k<32, 2><<<256, 256, 0, stream>>>(cgx, cgy, SSn, partials);
    reduce_hxy_k<<<64, 64, 0, stream>>>(partials, hxyD);
    finalize_k<<<1, 256, 0, stream>>>(hxyD, hxx, hyy, out, out + 4198401);
    hipMemcpyAsync(out + 4097, w, (size_t)Cn * Dn * sizeof(float),
                   hipMemcpyDeviceToDevice, stream);
}

// Round 4
// 175.037 us; speedup vs baseline: 1.9326x; 1.4273x over previous
//
#include <hip/hip_runtime.h>
#include <math.h>

#define Bn 64
#define Cn 64
#define Sn 128
#define Hn 512
#define Dn 65536
#define SSn 16384

using f32x4 = __attribute__((ext_vector_type(4))) float;
using bf16x8 = __attribute__((ext_vector_type(8))) short;

__device__ __forceinline__ float wredf(float v) {
#pragma unroll
    for (int o = 32; o > 0; o >>= 1) v += __shfl_down(v, o, 64);
    return v;
}

__device__ __forceinline__ unsigned short f2bf(float f) {
    unsigned int u = __float_as_uint(f);
    u += 0x7fffu + ((u >> 16) & 1u);
    return (unsigned short)(u >> 16);
}
__device__ __forceinline__ float bf2f(unsigned short h) {
    return __uint_as_float(((unsigned int)h) << 16);
}

// --- gram via bf16 3-split MFMA: G = M M^T (128x512 -> 128x128) ------------
// 1 block (8 waves) per matrix; wave w: rows 32*(w&3), cols 64*(w>>2).
// Fused: row sums (-> gsum, two col-halves) and trace (= sum sq -> x2/w2).
__global__ __launch_bounds__(512) void gram_k(const float* __restrict__ x,
                                              const float* __restrict__ w,
                                              float* __restrict__ gx,
                                              float* __restrict__ gy,
                                              float* __restrict__ gsum,
                                              float* __restrict__ x2,
                                              float* __restrict__ w2) {
    __shared__ unsigned short hi[128][72];
    __shared__ unsigned short lo[128][72];
    __shared__ float sred[8];
    const int mat = blockIdx.x;  // 0..127
    const float* src = (mat < Bn) ? (x + (size_t)mat * Dn) : (w + (size_t)(mat - Bn) * Dn);
    float* dst = (mat < Bn) ? (gx + (size_t)mat * SSn) : (gy + (size_t)(mat - Bn) * SSn);
    const int tid = threadIdx.x;
    const int lane = tid & 63;
    const int wv = tid >> 6;        // 0..7
    const int wm = wv & 3;          // row block (32 rows)
    const int wc = wv >> 1 >> 1;    // col block (64 cols) = wv>>2
    const int lrow = lane & 15;
    const int lk8 = (lane >> 4) * 8;
    f32x4 acc[2][4] = {};
    float ssq = 0.f;
    // staging indices: 4 float4 per thread per chunk
    const int f0 = tid;             // f, f+512, f+1024, f+1536
    float4 cur[4], nxt[4];
#pragma unroll
    for (int p = 0; p < 4; ++p) {
        const int f = f0 + 512 * p;
        cur[p] = *(const float4*)(src + (size_t)(f >> 4) * Hn + 0 + (f & 15) * 4);
    }
    for (int c = 0; c < 8; ++c) {
        // convert cur -> LDS (hi/lo), accumulate ssq
#pragma unroll
        for (int p = 0; p < 4; ++p) {
            const int f = f0 + 512 * p;
            const int r = f >> 4, c4 = (f & 15) * 4;
            float4 v = cur[p];
            ssq += v.x * v.x + v.y * v.y + v.z * v.z + v.w * v.w;
            unsigned short h0 = f2bf(v.x), h1 = f2bf(v.y), h2 = f2bf(v.z), h3 = f2bf(v.w);
            *(ushort4*)&hi[r][c4] = make_ushort4(h0, h1, h2, h3);
            *(ushort4*)&lo[r][c4] = make_ushort4(f2bf(v.x - bf2f(h0)), f2bf(v.y - bf2f(h1)),
                                                 f2bf(v.z - bf2f(h2)), f2bf(v.w - bf2f(h3)));
        }
        if (c < 7) {  // issue next-chunk loads; latency hides under MFMA phase
#pragma unroll
            for (int p = 0; p < 4; ++p) {
                const int f = f0 + 512 * p;
                nxt[p] = *(const float4*)(src + (size_t)(f >> 4) * Hn + (c + 1) * 64 + (f & 15) * 4);
            }
        }
        __syncthreads();
#pragma unroll
        for (int ks = 0; ks < 64; ks += 32) {
            bf16x8 ah[2], al[2], bh[4], bl[4];
#pragma unroll
            for (int i = 0; i < 2; ++i) {
                const int row = wm * 32 + i * 16 + lrow;
                ah[i] = *(const bf16x8*)&hi[row][ks + lk8];
                al[i] = *(const bf16x8*)&lo[row][ks + lk8];
            }
#pragma unroll
            for (int j = 0; j < 4; ++j) {
                const int row = wc * 64 + j * 16 + lrow;
                bh[j] = *(const bf16x8*)&hi[row][ks + lk8];
                bl[j] = *(const bf16x8*)&lo[row][ks + lk8];
            }
#pragma unroll
            for (int i = 0; i < 2; ++i)
#pragma unroll
                for (int j = 0; j < 4; ++j) {
                    acc[i][j] = __builtin_amdgcn_mfma_f32_16x16x32_bf16(ah[i], bh[j], acc[i][j], 0, 0, 0);
                    acc[i][j] = __builtin_amdgcn_mfma_f32_16x16x32_bf16(ah[i], bl[j], acc[i][j], 0, 0, 0);
                    acc[i][j] = __builtin_amdgcn_mfma_f32_16x16x32_bf16(al[i], bh[j], acc[i][j], 0, 0, 0);
                }
        }
        __syncthreads();
#pragma unroll
        for (int p = 0; p < 4; ++p) cur[p] = nxt[p];
    }
    // C write: row = (lane>>4)*4 + reg, col = lane&15 within 16x16 fragment
#pragma unroll
    for (int i = 0; i < 2; ++i)
#pragma unroll
        for (int j = 0; j < 4; ++j)
#pragma unroll
            for (int r = 0; r < 4; ++r) {
                const int grow = wm * 32 + i * 16 + (lane >> 4) * 4 + r;
                const int gcol = wc * 64 + j * 16 + (lane & 15);
                dst[(size_t)grow * Sn + gcol] = acc[i][j][r];
            }
    // row sums over this wave's 64 cols -> gsum[mat][wc][row]
#pragma unroll
    for (int i = 0; i < 2; ++i)
#pragma unroll
        for (int r = 0; r < 4; ++r) {
            float rs = acc[i][0][r] + acc[i][1][r] + acc[i][2][r] + acc[i][3][r];
            rs += __shfl_xor(rs, 1, 64);
            rs += __shfl_xor(rs, 2, 64);
            rs += __shfl_xor(rs, 4, 64);
            rs += __shfl_xor(rs, 8, 64);
            if ((lane & 15) == 0)
                gsum[mat * 256 + wc * 128 + wm * 32 + i * 16 + (lane >> 4) * 4 + r] = rs;
        }
    // trace = sum of squares of src (exact fp32)
    ssq = wredf(ssq);
    if (lane == 0) sred[wv] = ssq;
    __syncthreads();
    if (tid == 0) {
        float t = 0.f;
#pragma unroll
        for (int i = 0; i < 8; ++i) t += sred[i];
        if (mat < Bn) x2[mat] = t; else w2[mat - Bn] = t;
    }
}

// --- big split-K 64x64 dots: x.w^T over K=65536; 500 blocks, KC=128 --------
__global__ __launch_bounds__(256) void dotsbig_k(const float* __restrict__ A,
                                                 const float* __restrict__ Bm,
                                                 float* __restrict__ partials) {
    __shared__ float la[64][132];
    __shared__ float lb[64][132];
    const int tid = threadIdx.x;
    const int bid = blockIdx.x;  // 0..499
    const int ry = tid >> 4, tx = tid & 15;
    float acc[4][4] = {};
    const int nch = (bid < 12) ? 2 : 1;
    for (int c = 0; c < nch; ++c) {
        const int k0 = ((c == 0) ? bid : 500 + bid) * 128;
        __syncthreads();
        const int c4 = (tid & 31) * 4;
        for (int r = tid >> 5; r < 64; r += 8) {
            *(float4*)&la[r][c4] = *(const float4*)(A + (size_t)r * Dn + k0 + c4);
            *(float4*)&lb[r][c4] = *(const float4*)(Bm + (size_t)r * Dn + k0 + c4);
        }
        __syncthreads();
        for (int k = 0; k < 128; k += 4) {
            float4 av[4], bv[4];
#pragma unroll
            for (int i = 0; i < 4; ++i) av[i] = *(const float4*)&la[4 * ry + i][k];
#pragma unroll
            for (int j = 0; j < 4; ++j) bv[j] = *(const float4*)&lb[16 * j + tx][k];
#pragma unroll
            for (int i = 0; i < 4; ++i)
#pragma unroll
                for (int j = 0; j < 4; ++j)
                    acc[i][j] += av[i].x * bv[j].x + av[i].y * bv[j].y +
                                 av[i].z * bv[j].z + av[i].w * bv[j].w;
        }
    }
    float* p = partials + (size_t)bid * 4096;
#pragma unroll
    for (int i = 0; i < 4; ++i)
#pragma unroll
        for (int j = 0; j < 4; ++j)
            p[(4 * ry + i) * 64 + 16 * j + tx] = acc[i][j];
}

// --- small split-K dots (centered grams, K=16384), KC=64, 256 blocks -------
__global__ __launch_bounds__(256) void dotsmall_k(const float* __restrict__ A,
                                                  const float* __restrict__ Bm,
                                                  float* __restrict__ partials) {
    __shared__ float la[64][68];
    __shared__ float lb[64][68];
    const int tid = threadIdx.x;
    const int k0 = blockIdx.x * 64;
    const int ry = tid >> 4, tx = tid & 15;
    const int slc = (tid & 15) * 4;
    const int sr0 = tid >> 4;
    float acc[4][4] = {};
    for (int r = sr0; r < 64; r += 16) {
        *(float4*)&la[r][slc] = *(const float4*)(A + (size_t)r * SSn + k0 + slc);
        *(float4*)&lb[r][slc] = *(const float4*)(Bm + (size_t)r * SSn + k0 + slc);
    }
    __syncthreads();
    for (int k = 0; k < 64; k += 4) {
        float4 av[4], bv[4];
#pragma unroll
        for (int i = 0; i < 4; ++i) av[i] = *(const float4*)&la[4 * ry + i][k];
#pragma unroll
        for (int j = 0; j < 4; ++j) bv[j] = *(const float4*)&lb[16 * j + tx][k];
#pragma unroll
        for (int i = 0; i < 4; ++i)
#pragma unroll
            for (int j = 0; j < 4; ++j)
                acc[i][j] += av[i].x * bv[j].x + av[i].y * bv[j].y +
                             av[i].z * bv[j].z + av[i].w * bv[j].w;
    }
    float* p = partials + (size_t)blockIdx.x * 4096;
#pragma unroll
    for (int i = 0; i < 4; ++i)
#pragma unroll
        for (int j = 0; j < 4; ++j)
            p[(4 * ry + i) * 64 + 16 * j + tx] = acc[i][j];
}

// --- streaming centering, 4 blocks/mat; hxx/hyy partials -> hpart ----------
__global__ __launch_bounds__(256) void center_k(float* __restrict__ gx, float* __restrict__ gy,
                                                const float* __restrict__ gsum,
                                                float* __restrict__ hpart) {
    __shared__ float rm[128];
    __shared__ float gmv;
    __shared__ float red[4];
    const int mat = blockIdx.x >> 2;   // 0..127
    const int slab = blockIdx.x & 3;   // 32-row slab
    float* g = (mat < Bn) ? (gx + (size_t)mat * SSn) : (gy + (size_t)(mat - Bn) * SSn);
    const int tid = threadIdx.x;
    float rsv = 0.f;
    if (tid < 128) {
        rsv = gsum[mat * 256 + tid] + gsum[mat * 256 + 128 + tid];
        rm[tid] = rsv * (1.f / 128.f);
    }
    float gs = wredf(rsv);
    if ((tid & 63) == 0) red[tid >> 6] = gs;
    __syncthreads();
    if (tid == 0) gmv = (red[0] + red[1]) * (1.f / 16384.f);
    __syncthreads();
    const float gm = gmv;
    float sq = 0.f;
#pragma unroll
    for (int p = 0; p < 4; ++p) {
        const int f4 = slab * 1024 + tid + 256 * p;   // float4 index within matrix
        const int s = f4 >> 5;
        const float rms = rm[s] - gm;
        const float4 rmt = *(const float4*)&rm[(f4 & 31) * 4];
        float4 v = *(float4*)(g + 4 * (size_t)f4);
        float c0 = v.x - rms - rmt.x;
        float c1 = v.y - rms - rmt.y;
        float c2 = v.z - rms - rmt.z;
        float c3 = v.w - rms - rmt.w;
        sq += c0 * c0 + c1 * c1 + c2 * c2 + c3 * c3;
        *(float4*)(g + 4 * (size_t)f4) = make_float4(c0, c1, c2, c3);
    }
    sq = wredf(sq);
    if ((tid & 63) == 0) red[tid >> 6] = sq;
    __syncthreads();
    if (tid == 0) hpart[blockIdx.x] = red[0] + red[1] + red[2] + red[3];
}

// --- deterministic double reduce (P=500) -> dist ---------------------------
__global__ __launch_bounds__(64) void reduce_dist_k(const float* __restrict__ partials,
                                                    const float* __restrict__ x2,
                                                    const float* __restrict__ w2,
                                                    float* __restrict__ od) {
    const int i = blockIdx.x * 64 + threadIdx.x;  // 0..4095
    double s0 = 0, s1 = 0, s2 = 0, s3 = 0;
    for (int p = 0; p < 500; p += 4) {
        s0 += (double)partials[(size_t)p * 4096 + i];
        s1 += (double)partials[(size_t)(p + 1) * 4096 + i];
        s2 += (double)partials[(size_t)(p + 2) * 4096 + i];
        s3 += (double)partials[(size_t)(p + 3) * 4096 + i];
    }
    const int b = i >> 6, c = i & 63;
    float d2 = x2[b] + w2[c] - 2.f * (float)((s0 + s1) + (s2 + s3));
    od[i] = sqrtf(fmaxf(d2, 0.f));
}

// --- deterministic double reduce (P=256) -> hxy ----------------------------
__global__ __launch_bounds__(64) void reduce_hxy_k(const float* __restrict__ partials,
                                                   double* __restrict__ hxy) {
    const int i = blockIdx.x * 64 + threadIdx.x;
    double s0 = 0, s1 = 0, s2 = 0, s3 = 0;
    for (int p = 0; p < 256; p += 4) {
        s0 += (double)partials[(size_t)p * 4096 + i];
        s1 += (double)partials[(size_t)(p + 1) * 4096 + i];
        s2 += (double)partials[(size_t)(p + 2) * 4096 + i];
        s3 += (double)partials[(size_t)(p + 3) * 4096 + i];
    }
    hxy[i] = (s0 + s1) + (s2 + s3);
}

// --- fused: hxx/hyy from hpart, cka argmax, loss ---------------------------
__global__ void finalize_k(const double* __restrict__ hxy, const float* __restrict__ hpart,
                           float* __restrict__ out0, float* __restrict__ oidx) {
    __shared__ float shx[64], shy[64];
    __shared__ int sidx[64];
    __shared__ double sred[4];
    const int tid = threadIdx.x;  // 256
    if (tid < 128) {
        float s = hpart[4 * tid] + hpart[4 * tid + 1] + hpart[4 * tid + 2] + hpart[4 * tid + 3];
        if (tid < 64) shx[tid] = s; else shy[tid - 64] = s;
    }
    __syncthreads();
    if (tid < 64) {
        const int b = tid;
        double sx = sqrt((double)shx[b]);
        double best = -1e300; int bi = 0;
        for (int c = 0; c < Cn; ++c) {
            double r = fabs(hxy[b * Cn + c]) / (sx * sqrt((double)shy[c]));
            double v = -log(r + 1e-8);
            if (v > best) { best = v; bi = c; }
        }
        sidx[b] = bi;
        oidx[b] = (float)bi;
    }
    __syncthreads();
    double s = 0.0;
    for (int e = tid; e < 4096; e += 256) {
        const int b = e >> 6, c = e & 63;
        const int ic = sidx[c];
        s += fabs(hxy[b * Cn + ic]) / (sqrt((double)shx[b]) * sqrt((double)shy[ic]));
    }
#pragma unroll
    for (int o = 32; o > 0; o >>= 1) s += __shfl_down(s, o, 64);
    if ((tid & 63) == 0) sred[tid >> 6] = s;
    __syncthreads();
    if (tid == 0) {
        double t = sred[0] + sred[1] + sred[2] + sred[3];
        out0[0] = (float)(-log(t / 4096.0 + 1e-8));
    }
}

extern "C" void kernel_launch(void* const* d_in, const int* in_sizes, int n_in,
                              void* d_out, int out_size, void* d_ws, size_t ws_size,
                              hipStream_t stream) {
    const float* x = (const float*)d_in[0];   // (64, 65536)
    const float* w = (const float*)d_in[1];   // (64, 65536)
    float* out = (float*)d_out;
    // out: [0]=loss, [1..4096]=dist, [4097..4198400]=centroid copy, [4198401..]=idx
    // Scratch inside copy region [8192, 4198401); final memcpy overwrites it.
    float* cgx = out + 8192;                     // 1048576 fl
    float* cgy = out + 1056768;                  // 1048576 fl
    float* gsum = out + 2105344;                 // 32768 fl  [mat][2][128]
    float* partials = out + 2138112;             // 500*4096 = 2048000 fl (reused P=256)
    double* hxyD = (double*)(out + 4186112);     // 4096 dbl (8B aligned)
    float* x2 = out + 4194304;                   // 64
    float* w2 = out + 4194368;                   // 64
    float* hpart = out + 4194432;                // 512

    gram_k<<<128, 512, 0, stream>>>(x, w, cgx, cgy, gsum, x2, w2);
    dotsbig_k<<<500, 256, 0, stream>>>(x, w, partials);
    reduce_dist_k<<<64, 64, 0, stream>>>(partials, x2, w2, out + 1);
    center_k<<<512, 256, 0, stream>>>(cgx, cgy, gsum, hpart);
    dotsmall_k<<<256, 256, 0, stream>>>(cgx, cgy, partials);
    reduce_hxy_k<<<64, 64, 0, stream>>>(partials, hxyD);
    finalize_k<<<1, 256, 0, stream>>>(hxyD, hpart, out, out + 4198401);
    hipMemcpyAsync(out + 4097, w, (size_t)Cn * Dn * sizeof(float),
                   hipMemcpyDeviceToDevice, stream);
}

// Round 5
// 157.464 us; speedup vs baseline: 2.1483x; 1.1116x over previous
//
#include <hip/hip_runtime.h>
#include <math.h>

#define Bn 64
#define Cn 64
#define Sn 128
#define Hn 512
#define Dn 65536
#define SSn 16384

using f32x4 = __attribute__((ext_vector_type(4))) float;
using bf16x8 = __attribute__((ext_vector_type(8))) short;

__device__ __forceinline__ float wredf(float v) {
#pragma unroll
    for (int o = 32; o > 0; o >>= 1) v += __shfl_down(v, o, 64);
    return v;
}

__device__ __forceinline__ unsigned short f2bf(float f) {
    unsigned int u = __float_as_uint(f);
    u += 0x7fffu + ((u >> 16) & 1u);
    return (unsigned short)(u >> 16);
}
__device__ __forceinline__ float bf2f(unsigned short h) {
    return __uint_as_float(((unsigned int)h) << 16);
}

// --- gram via bf16 3-split MFMA: G = M M^T, uncentered -------------------
// 256 blocks = 2 per matrix (row halves), 256 threads (4 waves, 16 rows each).
// Fused: row sums -> rsT[s][mat] (transposed), sum(G^2) partial -> hpartG,
// trace (= sum sq of src) -> x2/w2.
__global__ __launch_bounds__(256) void gram_k(const float* __restrict__ x,
                                              const float* __restrict__ w,
                                              float* __restrict__ gx,
                                              float* __restrict__ gy,
                                              float* __restrict__ rsT,
                                              float* __restrict__ hpartG,
                                              float* __restrict__ x2,
                                              float* __restrict__ w2) {
    __shared__ unsigned short hi[128][72];
    __shared__ unsigned short lo[128][72];
    __shared__ float sredG[4], sredT[4];
    const int blk = blockIdx.x;
    const int mat = blk >> 1;          // 0..127
    const int half = blk & 1;
    const int r0 = half * 64;
    const float* src = (mat < Bn) ? (x + (size_t)mat * Dn) : (w + (size_t)(mat - Bn) * Dn);
    float* dst = (mat < Bn) ? (gx + (size_t)mat * SSn) : (gy + (size_t)(mat - Bn) * SSn);
    const int tid = threadIdx.x;
    const int lane = tid & 63;
    const int wv = tid >> 6;           // wave 0..3 -> rows r0+16*wv..+16
    const int lrow = lane & 15;
    const int lk8 = (lane >> 4) * 8;
    f32x4 acc[8] = {};
    float ssq = 0.f;
    float4 cur[8], nxt[8];
#pragma unroll
    for (int p = 0; p < 8; ++p) {
        const int f = tid + 256 * p;
        cur[p] = *(const float4*)(src + (size_t)(f >> 4) * Hn + (f & 15) * 4);
    }
    for (int c = 0; c < 8; ++c) {
#pragma unroll
        for (int p = 0; p < 8; ++p) {
            const int f = tid + 256 * p;
            const int r = f >> 4, c4 = (f & 15) * 4;
            float4 v = cur[p];
            ssq += v.x * v.x + v.y * v.y + v.z * v.z + v.w * v.w;
            unsigned short h0 = f2bf(v.x), h1 = f2bf(v.y), h2 = f2bf(v.z), h3 = f2bf(v.w);
            *(ushort4*)&hi[r][c4] = make_ushort4(h0, h1, h2, h3);
            *(ushort4*)&lo[r][c4] = make_ushort4(f2bf(v.x - bf2f(h0)), f2bf(v.y - bf2f(h1)),
                                                 f2bf(v.z - bf2f(h2)), f2bf(v.w - bf2f(h3)));
        }
        if (c < 7) {
#pragma unroll
            for (int p = 0; p < 8; ++p) {
                const int f = tid + 256 * p;
                nxt[p] = *(const float4*)(src + (size_t)(f >> 4) * Hn + (c + 1) * 64 + (f & 15) * 4);
            }
        }
        __syncthreads();
#pragma unroll
        for (int ks = 0; ks < 64; ks += 32) {
            const int arow = r0 + wv * 16 + lrow;
            bf16x8 ah = *(const bf16x8*)&hi[arow][ks + lk8];
            bf16x8 al = *(const bf16x8*)&lo[arow][ks + lk8];
#pragma unroll
            for (int j = 0; j < 8; ++j) {
                const int brow = j * 16 + lrow;
                bf16x8 bh = *(const bf16x8*)&hi[brow][ks + lk8];
                bf16x8 bl = *(const bf16x8*)&lo[brow][ks + lk8];
                acc[j] = __builtin_amdgcn_mfma_f32_16x16x32_bf16(ah, bh, acc[j], 0, 0, 0);
                acc[j] = __builtin_amdgcn_mfma_f32_16x16x32_bf16(ah, bl, acc[j], 0, 0, 0);
                acc[j] = __builtin_amdgcn_mfma_f32_16x16x32_bf16(al, bh, acc[j], 0, 0, 0);
            }
        }
        __syncthreads();
#pragma unroll
        for (int p = 0; p < 8; ++p) cur[p] = nxt[p];
    }
    // C write: within 16x16 frag, col = lane&15, row = (lane>>4)*4 + r
    const int crow4 = (lane >> 4) * 4;
    float sq = 0.f;
#pragma unroll
    for (int j = 0; j < 8; ++j)
#pragma unroll
        for (int r = 0; r < 4; ++r) {
            const float v = acc[j][r];
            dst[(size_t)(r0 + wv * 16 + crow4 + r) * Sn + j * 16 + lrow] = v;
            sq += v * v;
        }
    // row sums (full 128 cols within wave)
#pragma unroll
    for (int r = 0; r < 4; ++r) {
        float rs = 0.f;
#pragma unroll
        for (int j = 0; j < 8; ++j) rs += acc[j][r];
        rs += __shfl_xor(rs, 1, 64);
        rs += __shfl_xor(rs, 2, 64);
        rs += __shfl_xor(rs, 4, 64);
        rs += __shfl_xor(rs, 8, 64);
        if (lrow == 0) rsT[(size_t)(r0 + wv * 16 + crow4 + r) * 128 + mat] = rs;
    }
    sq = wredf(sq);
    ssq = wredf(ssq);
    if (lane == 0) { sredG[wv] = sq; sredT[wv] = ssq; }
    __syncthreads();
    if (tid == 0) {
        hpartG[blk] = sredG[0] + sredG[1] + sredG[2] + sredG[3];
        if (half == 0) {
            float t = sredT[0] + sredT[1] + sredT[2] + sredT[3];
            if (mat < Bn) x2[mat] = t; else w2[mat - Bn] = t;
        }
    }
}

// --- S[m], hxx/hyy from closed form: hxx = sumG2 - (2/n)Sum rs^2 + S^2/n^2
__global__ void sumS_k(const float* __restrict__ rsT, const float* __restrict__ hpartG,
                       float* __restrict__ Sv, float* __restrict__ hxx,
                       float* __restrict__ hyy) {
    const int m = threadIdx.x;  // 128
    float s = 0.f, q = 0.f;
    for (int t = 0; t < 128; ++t) {
        float v = rsT[t * 128 + m];
        s += v; q += v * v;
    }
    Sv[m] = s;
    double val = (double)hpartG[2 * m] + (double)hpartG[2 * m + 1]
               - (double)q * (1.0 / 64.0) + (double)s * (double)s * (1.0 / 16384.0);
    if (m < 64) hxx[m] = (float)val; else hyy[m - 64] = (float)val;
}

// --- big split-K 64x64 dots over K=65536; 512 blocks, KC=64 x 2 chunks ----
__global__ __launch_bounds__(256) void dotsbig_k(const float* __restrict__ A,
                                                 const float* __restrict__ Bm,
                                                 float* __restrict__ partials) {
    __shared__ float la[64][68];
    __shared__ float lb[64][68];
    const int tid = threadIdx.x;
    const int ry = tid >> 4, tx = tid & 15;
    const int slc = (tid & 15) * 4, sr0 = tid >> 4;
    float acc[4][4] = {};
    for (int c = 0; c < 2; ++c) {
        const int k0 = blockIdx.x * 128 + c * 64;
        __syncthreads();
        for (int r = sr0; r < 64; r += 16) {
            *(float4*)&la[r][slc] = *(const float4*)(A + (size_t)r * Dn + k0 + slc);
            *(float4*)&lb[r][slc] = *(const float4*)(Bm + (size_t)r * Dn + k0 + slc);
        }
        __syncthreads();
        for (int k = 0; k < 64; k += 4) {
            float4 av[4], bv[4];
#pragma unroll
            for (int i = 0; i < 4; ++i) av[i] = *(const float4*)&la[4 * ry + i][k];
#pragma unroll
            for (int j = 0; j < 4; ++j) bv[j] = *(const float4*)&lb[16 * j + tx][k];
#pragma unroll
            for (int i = 0; i < 4; ++i)
#pragma unroll
                for (int j = 0; j < 4; ++j)
                    acc[i][j] += av[i].x * bv[j].x + av[i].y * bv[j].y +
                                 av[i].z * bv[j].z + av[i].w * bv[j].w;
        }
    }
    float* p = partials + (size_t)blockIdx.x * 4096;
#pragma unroll
    for (int i = 0; i < 4; ++i)
#pragma unroll
        for (int j = 0; j < 4; ++j)
            p[(4 * ry + i) * 64 + 16 * j + tx] = acc[i][j];
}

// --- small split-K dots (uncentered grams, K=16384), KC=64, 256 blocks ----
__global__ __launch_bounds__(256) void dotsmall_k(const float* __restrict__ A,
                                                  const float* __restrict__ Bm,
                                                  float* __restrict__ partials) {
    __shared__ float la[64][68];
    __shared__ float lb[64][68];
    const int tid = threadIdx.x;
    const int k0 = blockIdx.x * 64;
    const int ry = tid >> 4, tx = tid & 15;
    const int slc = (tid & 15) * 4, sr0 = tid >> 4;
    float acc[4][4] = {};
    for (int r = sr0; r < 64; r += 16) {
        *(float4*)&la[r][slc] = *(const float4*)(A + (size_t)r * SSn + k0 + slc);
        *(float4*)&lb[r][slc] = *(const float4*)(Bm + (size_t)r * SSn + k0 + slc);
    }
    __syncthreads();
    for (int k = 0; k < 64; k += 4) {
        float4 av[4], bv[4];
#pragma unroll
        for (int i = 0; i < 4; ++i) av[i] = *(const float4*)&la[4 * ry + i][k];
#pragma unroll
        for (int j = 0; j < 4; ++j) bv[j] = *(const float4*)&lb[16 * j + tx][k];
#pragma unroll
        for (int i = 0; i < 4; ++i)
#pragma unroll
            for (int j = 0; j < 4; ++j)
                acc[i][j] += av[i].x * bv[j].x + av[i].y * bv[j].y +
                             av[i].z * bv[j].z + av[i].w * bv[j].w;
    }
    float* p = partials + (size_t)blockIdx.x * 4096;
#pragma unroll
    for (int i = 0; i < 4; ++i)
#pragma unroll
        for (int j = 0; j < 4; ++j)
            p[(4 * ry + i) * 64 + 16 * j + tx] = acc[i][j];
}

// --- wide reduce (P=512) -> dist; 256 blocks x 256 thr (16 out x 16 slices)
__global__ __launch_bounds__(256) void reduce_dist_k(const float* __restrict__ partials,
                                                     const float* __restrict__ x2,
                                                     const float* __restrict__ w2,
                                                     float* __restrict__ od) {
    __shared__ double red[16][17];
    const int o = threadIdx.x & 15;
    const int sl = threadIdx.x >> 4;
    const int i = blockIdx.x * 16 + o;
    double s0 = 0, s1 = 0;
    for (int t = 0; t < 32; t += 2) {
        s0 += (double)partials[(size_t)(sl + 16 * t) * 4096 + i];
        s1 += (double)partials[(size_t)(sl + 16 * (t + 1)) * 4096 + i];
    }
    red[sl][o] = s0 + s1;
    __syncthreads();
    if (threadIdx.x < 16) {
        const int ii = blockIdx.x * 16 + threadIdx.x;
        double s = 0;
        for (int t = 0; t < 16; ++t) s += red[t][threadIdx.x];
        const int b = ii >> 6, cc = ii & 63;
        float d2 = x2[b] + w2[cc] - 2.f * (float)s;
        od[ii] = sqrtf(fmaxf(d2, 0.f));
    }
}

// --- wide reduce (P=256) + centering correction -> hxy ---------------------
// hxy = <Gx,Gy> - (1/64)*Sum_s rsx_s*rsy_s + Sx*Sy/16384
__global__ __launch_bounds__(256) void reduce_hxy_k(const float* __restrict__ partials,
                                                    const float* __restrict__ rsT,
                                                    const float* __restrict__ Sv,
                                                    double* __restrict__ hxy) {
    __shared__ double red[16][17];
    const int o = threadIdx.x & 15;
    const int sl = threadIdx.x >> 4;
    const int i = blockIdx.x * 16 + o;
    const int b = i >> 6, cc = i & 63;
    double s = 0;
    for (int t = 0; t < 16; ++t)
        s += (double)partials[(size_t)(sl + 16 * t) * 4096 + i];
    double corr = 0;
#pragma unroll
    for (int t = 0; t < 8; ++t) {
        const int ss = sl * 8 + t;
        corr += (double)rsT[ss * 128 + b] * (double)rsT[ss * 128 + 64 + cc];
    }
    red[sl][o] = s - corr * (1.0 / 64.0);
    __syncthreads();
    if (threadIdx.x < 16) {
        const int ii = blockIdx.x * 16 + threadIdx.x;
        const int b2 = ii >> 6, c2 = ii & 63;
        double t2 = 0;
        for (int t = 0; t < 16; ++t) t2 += red[t][threadIdx.x];
        t2 += (double)Sv[b2] * (double)Sv[64 + c2] * (1.0 / 16384.0);
        hxy[ii] = t2;
    }
}

// --- fused: cka argmax per row, then loss via hxy2[b][c] = hxy[b][idx[c]] --
__global__ void finalize_k(const double* __restrict__ hxy, const float* __restrict__ hxx,
                           const float* __restrict__ hyy, float* __restrict__ out0,
                           float* __restrict__ oidx) {
    __shared__ int sidx[64];
    __shared__ double sred[4];
    const int tid = threadIdx.x;  // 256
    if (tid < 64) {
        const int b = tid;
        double sx = sqrt((double)hxx[b]);
        double best = -1e300; int bi = 0;
        for (int c = 0; c < Cn; ++c) {
            double r = fabs(hxy[b * Cn + c]) / (sx * sqrt((double)hyy[c]));
            double v = -log(r + 1e-8);
            if (v > best) { best = v; bi = c; }
        }
        sidx[b] = bi;
        oidx[b] = (float)bi;
    }
    __syncthreads();
    double s = 0.0;
    for (int e = tid; e < 4096; e += 256) {
        const int b = e >> 6, c = e & 63;
        const int ic = sidx[c];
        s += fabs(hxy[b * Cn + ic]) / (sqrt((double)hxx[b]) * sqrt((double)hyy[ic]));
    }
#pragma unroll
    for (int o = 32; o > 0; o >>= 1) s += __shfl_down(s, o, 64);
    if ((tid & 63) == 0) sred[tid >> 6] = s;
    __syncthreads();
    if (tid == 0) {
        double t = sred[0] + sred[1] + sred[2] + sred[3];
        out0[0] = (float)(-log(t / 4096.0 + 1e-8));
    }
}

extern "C" void kernel_launch(void* const* d_in, const int* in_sizes, int n_in,
                              void* d_out, int out_size, void* d_ws, size_t ws_size,
                              hipStream_t stream) {
    const float* x = (const float*)d_in[0];   // (64, 65536)
    const float* w = (const float*)d_in[1];   // (64, 65536)
    float* out = (float*)d_out;
    // out: [0]=loss, [1..4096]=dist, [4097..4198400]=centroid copy, [4198401..]=idx
    // Scratch in d_ws (~256 MiB per harness fill evidence); ~17 MB used.
    float* ws = (float*)d_ws;
    float* gx = ws;                           // 1048576
    float* gy = ws + 1048576;                 // 1048576
    float* partials = ws + 2097152;           // 512*4096 = 2097152
    float* rsT = ws + 4194304;                // 128*128 (s-major, [s][mat])
    float* hpartG = ws + 4210688;             // 256
    float* Sv = ws + 4210944;                 // 128
    float* x2 = ws + 4211072;                 // 64
    float* w2 = ws + 4211136;                 // 64
    float* hxx = ws + 4211200;                // 64
    float* hyy = ws + 4211264;                // 64
    double* hxyD = (double*)(ws + 4211328);   // 4096 doubles (8B aligned)

    gram_k<<<256, 256, 0, stream>>>(x, w, gx, gy, rsT, hpartG, x2, w2);
    dotsbig_k<<<512, 256, 0, stream>>>(x, w, partials);
    reduce_dist_k<<<256, 256, 0, stream>>>(partials, x2, w2, out + 1);
    dotsmall_k<<<256, 256, 0, stream>>>(gx, gy, partials);
    sumS_k<<<1, 128, 0, stream>>>(rsT, hpartG, Sv, hxx, hyy);
    reduce_hxy_k<<<256, 256, 0, stream>>>(partials, rsT, Sv, hxyD);
    finalize_k<<<1, 256, 0, stream>>>(hxyD, hxx, hyy, out, out + 4198401);
    hipMemcpyAsync(out + 4097, w, (size_t)Cn * Dn * sizeof(float),
                   hipMemcpyDeviceToDevice, stream);
}

// Round 6
// 120.400 us; speedup vs baseline: 2.8096x; 1.3078x over previous
//
#include <hip/hip_runtime.h>
#include <math.h>

#define Bn 64
#define Cn 64
#define Sn 128
#define Hn 512
#define Dn 65536
#define SSn 16384

using f32x4 = __attribute__((ext_vector_type(4))) float;
using bf16x8 = __attribute__((ext_vector_type(8))) short;
using u16x8 = __attribute__((ext_vector_type(8))) unsigned short;

__device__ __forceinline__ float wredf(float v) {
#pragma unroll
    for (int o = 32; o > 0; o >>= 1) v += __shfl_down(v, o, 64);
    return v;
}

__device__ __forceinline__ unsigned short f2bf(float f) {
    unsigned int u = __float_as_uint(f);
    u += 0x7fffu + ((u >> 16) & 1u);
    return (unsigned short)(u >> 16);
}
__device__ __forceinline__ float bf2f(unsigned short h) {
    return __uint_as_float(((unsigned int)h) << 16);
}

// ===== Kernel A: gram (even bid<512) | dist-dots (odd bid<512) | copy (>=512)
__global__ __launch_bounds__(256) void kA(const float* __restrict__ x,
                                          const float* __restrict__ w,
                                          unsigned short* __restrict__ ghi,
                                          unsigned short* __restrict__ glo,
                                          float* __restrict__ rsT,
                                          float* __restrict__ hpartG,
                                          float* __restrict__ x2,
                                          float* __restrict__ w2,
                                          float* __restrict__ partials,
                                          float* __restrict__ outcpy) {
    __shared__ __align__(16) unsigned char smem[36864];
    const int bid = blockIdx.x;
    const int tid = threadIdx.x;
    if (bid >= 512) {  // ---- copy w -> out+4097 (dst only 4B-aligned) ----
        const int cid = bid - 512;  // 0..127
        const float4* wsrc = (const float4*)w;
#pragma unroll 4
        for (int p = 0; p < 32; ++p) {
            const size_t f4i = (size_t)cid * 8192 + tid + 256 * p;
            float4 v = wsrc[f4i];
            float* dst = outcpy + 4 * f4i;
            dst[0] = v.x; dst[1] = v.y; dst[2] = v.z; dst[3] = v.w;
        }
        return;
    }
    const int lane = tid & 63;
    const int wv = tid >> 6;
    const int lrow = lane & 15;
    const int lk8 = (lane >> 4) * 8;
    const int crow4 = (lane >> 4) * 4;
    if ((bid & 1) == 0) {  // ---- gram: G = M M^T, split-stored bf16 hi/lo ----
        __shared__ float sredG[4], sredT[4];
        const int gid = bid >> 1;        // 0..255
        const int mat = gid >> 1, half = gid & 1, r0 = half * 64;
        const float* src = (mat < Bn) ? (x + (size_t)mat * Dn) : (w + (size_t)(mat - Bn) * Dn);
        unsigned short* dhi = ghi + (size_t)mat * SSn;
        unsigned short* dlo = glo + (size_t)mat * SSn;
        unsigned short (*hi)[72] = (unsigned short(*)[72])smem;
        unsigned short (*lo)[72] = (unsigned short(*)[72])(smem + 18432);
        f32x4 acc[8] = {};
        float ssq = 0.f;
        float4 cur[8], nxt[8];
#pragma unroll
        for (int p = 0; p < 8; ++p) {
            const int f = tid + 256 * p;
            cur[p] = *(const float4*)(src + (size_t)(f >> 4) * Hn + (f & 15) * 4);
        }
        for (int c = 0; c < 8; ++c) {
#pragma unroll
            for (int p = 0; p < 8; ++p) {
                const int f = tid + 256 * p;
                const int r = f >> 4, c4 = (f & 15) * 4;
                float4 v = cur[p];
                ssq += v.x * v.x + v.y * v.y + v.z * v.z + v.w * v.w;
                unsigned short h0 = f2bf(v.x), h1 = f2bf(v.y), h2 = f2bf(v.z), h3 = f2bf(v.w);
                *(ushort4*)&hi[r][c4] = make_ushort4(h0, h1, h2, h3);
                *(ushort4*)&lo[r][c4] = make_ushort4(f2bf(v.x - bf2f(h0)), f2bf(v.y - bf2f(h1)),
                                                     f2bf(v.z - bf2f(h2)), f2bf(v.w - bf2f(h3)));
            }
            if (c < 7) {
#pragma unroll
                for (int p = 0; p < 8; ++p) {
                    const int f = tid + 256 * p;
                    nxt[p] = *(const float4*)(src + (size_t)(f >> 4) * Hn + (c + 1) * 64 + (f & 15) * 4);
                }
            }
            __syncthreads();
#pragma unroll
            for (int ks = 0; ks < 64; ks += 32) {
                const int arow = r0 + wv * 16 + lrow;
                bf16x8 ah = *(const bf16x8*)&hi[arow][ks + lk8];
                bf16x8 al = *(const bf16x8*)&lo[arow][ks + lk8];
#pragma unroll
                for (int j = 0; j < 8; ++j) {
                    const int brow = j * 16 + lrow;
                    bf16x8 bh = *(const bf16x8*)&hi[brow][ks + lk8];
                    bf16x8 bl = *(const bf16x8*)&lo[brow][ks + lk8];
                    acc[j] = __builtin_amdgcn_mfma_f32_16x16x32_bf16(ah, bh, acc[j], 0, 0, 0);
                    acc[j] = __builtin_amdgcn_mfma_f32_16x16x32_bf16(ah, bl, acc[j], 0, 0, 0);
                    acc[j] = __builtin_amdgcn_mfma_f32_16x16x32_bf16(al, bh, acc[j], 0, 0, 0);
                }
            }
            __syncthreads();
#pragma unroll
            for (int p = 0; p < 8; ++p) cur[p] = nxt[p];
        }
        float sq = 0.f;
#pragma unroll
        for (int j = 0; j < 8; ++j)
#pragma unroll
            for (int r = 0; r < 4; ++r) {
                const float v = acc[j][r];
                sq += v * v;
                const size_t o = (size_t)(r0 + wv * 16 + crow4 + r) * Sn + j * 16 + lrow;
                unsigned short h = f2bf(v);
                dhi[o] = h;
                dlo[o] = f2bf(v - bf2f(h));
            }
#pragma unroll
        for (int r = 0; r < 4; ++r) {
            float rs = 0.f;
#pragma unroll
            for (int j = 0; j < 8; ++j) rs += acc[j][r];
            rs += __shfl_xor(rs, 1, 64);
            rs += __shfl_xor(rs, 2, 64);
            rs += __shfl_xor(rs, 4, 64);
            rs += __shfl_xor(rs, 8, 64);
            if (lrow == 0) rsT[(size_t)(r0 + wv * 16 + crow4 + r) * 128 + mat] = rs;
        }
        sq = wredf(sq);
        ssq = wredf(ssq);
        if (lane == 0) { sredG[wv] = sq; sredT[wv] = ssq; }
        __syncthreads();
        if (tid == 0) {
            hpartG[gid] = sredG[0] + sredG[1] + sredG[2] + sredG[3];
            if (half == 0) {
                float t = sredT[0] + sredT[1] + sredT[2] + sredT[3];
                if (mat < Bn) x2[mat] = t; else w2[mat - Bn] = t;
            }
        }
    } else {  // ---- dist dots: hi-only bf16 MFMA, K-slice 256 per block ----
        const int did = bid >> 1;  // 0..255
        unsigned short (*la)[136] = (unsigned short(*)[136])smem;
        unsigned short (*lb)[136] = (unsigned short(*)[136])(smem + 17408);
        f32x4 acc[4] = {};
        for (int c = 0; c < 2; ++c) {
            const int k0 = did * 256 + c * 128;
            __syncthreads();
#pragma unroll
            for (int p = 0; p < 8; ++p) {
                const int f = tid + 256 * p;  // 64 rows x 32 f4
                const int row = f >> 5, c4 = (f & 31) * 4;
                float4 vx = *(const float4*)(x + (size_t)row * Dn + k0 + c4);
                float4 vw = *(const float4*)(w + (size_t)row * Dn + k0 + c4);
                *(ushort4*)&la[row][c4] = make_ushort4(f2bf(vx.x), f2bf(vx.y), f2bf(vx.z), f2bf(vx.w));
                *(ushort4*)&lb[row][c4] = make_ushort4(f2bf(vw.x), f2bf(vw.y), f2bf(vw.z), f2bf(vw.w));
            }
            __syncthreads();
#pragma unroll
            for (int ks = 0; ks < 4; ++ks) {
                bf16x8 a = *(const bf16x8*)&la[wv * 16 + lrow][ks * 32 + lk8];
#pragma unroll
                for (int j = 0; j < 4; ++j) {
                    bf16x8 b = *(const bf16x8*)&lb[j * 16 + lrow][ks * 32 + lk8];
                    acc[j] = __builtin_amdgcn_mfma_f32_16x16x32_bf16(a, b, acc[j], 0, 0, 0);
                }
            }
        }
        float* p = partials + (size_t)did * 4096;
#pragma unroll
        for (int j = 0; j < 4; ++j)
#pragma unroll
            for (int r = 0; r < 4; ++r)
                p[(wv * 16 + crow4 + r) * 64 + j * 16 + lrow] = acc[j][r];
    }
}

// ===== Kernel B: hxy-dots (bid<256) | dist-reduce (256..319) | sumS (320) ===
__global__ __launch_bounds__(256) void kB(const unsigned short* __restrict__ ghi,
                                          const unsigned short* __restrict__ glo,
                                          const float* __restrict__ partials,
                                          const float* __restrict__ rsT,
                                          const float* __restrict__ hpartG,
                                          const float* __restrict__ x2,
                                          const float* __restrict__ w2,
                                          float* __restrict__ partials2,
                                          float* __restrict__ Sv,
                                          float* __restrict__ hxx,
                                          float* __restrict__ hyy,
                                          float* __restrict__ od) {
    __shared__ __align__(16) unsigned char smem[36864];
    const int bid = blockIdx.x;
    const int tid = threadIdx.x;
    if (bid < 256) {  // ---- hxy dots on pre-split grams, 3-split MFMA ----
        unsigned short (*lah)[72] = (unsigned short(*)[72])smem;
        unsigned short (*lal)[72] = (unsigned short(*)[72])(smem + 9216);
        unsigned short (*lbh)[72] = (unsigned short(*)[72])(smem + 18432);
        unsigned short (*lbl)[72] = (unsigned short(*)[72])(smem + 27648);
        const int k0 = bid * 64;
#pragma unroll
        for (int i = 0; i < 2; ++i) {
            const int idx = tid + 256 * i;          // 512 = 64 mats x 8 u16x8
            const int mat = idx >> 3, c8 = (idx & 7) * 8;
            *(u16x8*)&lah[mat][c8] = *(const u16x8*)(ghi + (size_t)mat * SSn + k0 + c8);
            *(u16x8*)&lal[mat][c8] = *(const u16x8*)(glo + (size_t)mat * SSn + k0 + c8);
            *(u16x8*)&lbh[mat][c8] = *(const u16x8*)(ghi + (size_t)(64 + mat) * SSn + k0 + c8);
            *(u16x8*)&lbl[mat][c8] = *(const u16x8*)(glo + (size_t)(64 + mat) * SSn + k0 + c8);
        }
        __syncthreads();
        const int lane = tid & 63;
        const int wv = tid >> 6;
        const int lrow = lane & 15;
        const int lk8 = (lane >> 4) * 8;
        const int crow4 = (lane >> 4) * 4;
        f32x4 acc[4] = {};
#pragma unroll
        for (int ks = 0; ks < 64; ks += 32) {
            bf16x8 ah = *(const bf16x8*)&lah[wv * 16 + lrow][ks + lk8];
            bf16x8 al = *(const bf16x8*)&lal[wv * 16 + lrow][ks + lk8];
#pragma unroll
            for (int j = 0; j < 4; ++j) {
                bf16x8 bh = *(const bf16x8*)&lbh[j * 16 + lrow][ks + lk8];
                bf16x8 bl = *(const bf16x8*)&lbl[j * 16 + lrow][ks + lk8];
                acc[j] = __builtin_amdgcn_mfma_f32_16x16x32_bf16(ah, bh, acc[j], 0, 0, 0);
                acc[j] = __builtin_amdgcn_mfma_f32_16x16x32_bf16(ah, bl, acc[j], 0, 0, 0);
                acc[j] = __builtin_amdgcn_mfma_f32_16x16x32_bf16(al, bh, acc[j], 0, 0, 0);
            }
        }
        float* p = partials2 + (size_t)bid * 4096;
#pragma unroll
        for (int j = 0; j < 4; ++j)
#pragma unroll
            for (int r = 0; r < 4; ++r)
                p[(wv * 16 + crow4 + r) * 64 + j * 16 + lrow] = acc[j][r];
    } else if (bid < 320) {  // ---- dist reduce (P=256) ----
        double* red = (double*)smem;  // [4][64]
        const int b2 = bid - 256;     // 0..63 (= b row)
        const int o = tid & 63, sl = tid >> 6;
        const int i = b2 * 64 + o;
        double s0 = 0, s1 = 0;
        for (int t = 0; t < 64; t += 2) {
            s0 += (double)partials[(size_t)(sl + 4 * t) * 4096 + i];
            s1 += (double)partials[(size_t)(sl + 4 * (t + 1)) * 4096 + i];
        }
        red[sl * 64 + o] = s0 + s1;
        __syncthreads();
        if (tid < 64) {
            double t = red[tid] + red[64 + tid] + red[128 + tid] + red[192 + tid];
            float d2 = x2[b2] + w2[tid] - 2.f * (float)t;
            od[b2 * 64 + tid] = sqrtf(fmaxf(d2, 0.f));
        }
    } else {  // ---- sumS: S[m], hxx/hyy closed form ----
        const int m = tid;  // use first 128 threads
        if (m < 128) {
            float s = 0.f, q = 0.f;
            for (int t = 0; t < 128; ++t) {
                float v = rsT[t * 128 + m];
                s += v; q += v * v;
            }
            Sv[m] = s;
            double val = (double)hpartG[2 * m] + (double)hpartG[2 * m + 1]
                       - (double)q * (1.0 / 64.0) + (double)s * (double)s * (1.0 / 16384.0);
            if (m < 64) hxx[m] = (float)val; else hyy[m - 64] = (float)val;
        }
    }
}

// ===== Kernel C: hxy reduce + centering corrections (grid 64 x 256) ========
__global__ __launch_bounds__(256) void kC(const float* __restrict__ partials2,
                                          const float* __restrict__ rsT,
                                          const float* __restrict__ Sv,
                                          double* __restrict__ hxy) {
    __shared__ double red[256];
    const int b = blockIdx.x;       // b row
    const int o = threadIdx.x & 63; // c
    const int sl = threadIdx.x >> 6;
    const int i = b * 64 + o;
    double s0 = 0, s1 = 0;
    for (int t = 0; t < 64; t += 2) {
        s0 += (double)partials2[(size_t)(sl + 4 * t) * 4096 + i];
        s1 += (double)partials2[(size_t)(sl + 4 * (t + 1)) * 4096 + i];
    }
    double corr = 0;
    for (int t = 0; t < 32; ++t) {
        const int ss = sl * 32 + t;
        corr += (double)rsT[ss * 128 + b] * (double)rsT[ss * 128 + 64 + o];
    }
    red[sl * 64 + o] = (s0 + s1) - corr * (1.0 / 64.0);
    __syncthreads();
    if (threadIdx.x < 64) {
        double t = red[threadIdx.x] + red[64 + threadIdx.x] +
                   red[128 + threadIdx.x] + red[192 + threadIdx.x];
        t += (double)Sv[b] * (double)Sv[64 + threadIdx.x] * (1.0 / 16384.0);
        hxy[b * 64 + threadIdx.x] = t;
    }
}

// ===== Kernel D: argmin-based argmax (no logs in loop) + loss ==============
__global__ void finalize_k(const double* __restrict__ hxy, const float* __restrict__ hxx,
                           const float* __restrict__ hyy, float* __restrict__ out0,
                           float* __restrict__ oidx) {
    __shared__ double inv_sx[64], inv_sy[64];
    __shared__ int sidx[64];
    __shared__ double sred[4];
    const int tid = threadIdx.x;  // 256
    if (tid < 64) {
        inv_sx[tid] = 1.0 / sqrt((double)hxx[tid]);
        inv_sy[tid] = 1.0 / sqrt((double)hyy[tid]);
    }
    __syncthreads();
    if (tid < 64) {
        const int b = tid;
        double best = 1e300; int bi = 0;
        for (int c = 0; c < Cn; ++c) {
            double v = fabs(hxy[b * Cn + c]) * inv_sy[c];
            if (v < best) { best = v; bi = c; }   // argmin r == argmax -log(r+eps); first-wins
        }
        sidx[b] = bi;
        oidx[b] = (float)bi;
    }
    __syncthreads();
    double s = 0.0;
    for (int e = tid; e < 4096; e += 256) {
        const int b = e >> 6, c = e & 63;
        const int ic = sidx[c];
        s += fabs(hxy[b * Cn + ic]) * inv_sx[b] * inv_sy[ic];
    }
#pragma unroll
    for (int o = 32; o > 0; o >>= 1) s += __shfl_down(s, o, 64);
    if ((tid & 63) == 0) sred[tid >> 6] = s;
    __syncthreads();
    if (tid == 0) {
        double t = sred[0] + sred[1] + sred[2] + sred[3];
        out0[0] = (float)(-log(t / 4096.0 + 1e-8));
    }
}

extern "C" void kernel_launch(void* const* d_in, const int* in_sizes, int n_in,
                              void* d_out, int out_size, void* d_ws, size_t ws_size,
                              hipStream_t stream) {
    const float* x = (const float*)d_in[0];   // (64, 65536)
    const float* w = (const float*)d_in[1];   // (64, 65536)
    float* out = (float*)d_out;
    // out: [0]=loss, [1..4096]=dist, [4097..4198400]=centroid copy, [4198401..]=idx
    float* ws = (float*)d_ws;
    unsigned short* ghi = (unsigned short*)ws;            // 128*16384 u16 = 1,048,576 fl
    unsigned short* glo = (unsigned short*)(ws + 1048576);
    float* partials  = ws + 2097152;                      // 256*4096
    float* partials2 = ws + 3145728;                      // 256*4096
    float* rsT    = ws + 4194304;                         // 128*128 [s][mat]
    float* hpartG = ws + 4210688;                         // 256
    float* Sv     = ws + 4210944;                         // 128
    float* x2     = ws + 4211072;                         // 64
    float* w2     = ws + 4211136;                         // 64
    float* hxx    = ws + 4211200;                         // 64
    float* hyy    = ws + 4211264;                         // 64
    double* hxyD  = (double*)(ws + 4211328);              // 4096 doubles

    kA<<<640, 256, 0, stream>>>(x, w, ghi, glo, rsT, hpartG, x2, w2, partials, out + 4097);
    kB<<<321, 256, 0, stream>>>(ghi, glo, partials, rsT, hpartG, x2, w2,
                                partials2, Sv, hxx, hyy, out + 1);
    kC<<<64, 256, 0, stream>>>(partials2, rsT, Sv, hxyD);
    finalize_k<<<1, 256, 0, stream>>>(hxyD, hxx, hyy, out, out + 4198401);
}

// Round 8
// 113.013 us; speedup vs baseline: 2.9932x; 1.0654x over previous
//
#include <hip/hip_runtime.h>
#include <math.h>

#define Bn 64
#define Cn 64
#define Sn 128
#define Hn 512
#define Dn 65536
#define SSn 16384

using f32x4 = __attribute__((ext_vector_type(4))) float;
using bf16x8 = __attribute__((ext_vector_type(8))) short;

__device__ __forceinline__ float wredf(float v) {
#pragma unroll
    for (int o = 32; o > 0; o >>= 1) v += __shfl_down(v, o, 64);
    return v;
}

__device__ __forceinline__ unsigned short f2bf(float f) {
    unsigned int u = __float_as_uint(f);
    u += 0x7fffu + ((u >> 16) & 1u);
    return (unsigned short)(u >> 16);
}
__device__ __forceinline__ float bf2f(unsigned short h) {
    return __uint_as_float(((unsigned int)h) << 16);
}

// ===== Kernel A: gram (bid<128) | dist-dots (128..255) | copy (256..319) ====
// 512 threads. Gram: 1 block/mat, convert-once, bf16 3-split MFMA, fp32 G
// stored in a lane-contiguous PERMUTED layout (dot over G is permutation-
// invariant, so kB never needs the real (s,t) indexing; rsT/x2/hpartG come
// from registers with true row ids).
__global__ __launch_bounds__(512) void kA(const float* __restrict__ x,
                                          const float* __restrict__ w,
                                          float* __restrict__ gF,
                                          float* __restrict__ rsT,
                                          float* __restrict__ hpartG,
                                          float* __restrict__ x2,
                                          float* __restrict__ w2,
                                          float* __restrict__ partials,
                                          float* __restrict__ outcpy) {
    __shared__ __align__(16) unsigned char smem[67584];
    const int bid = blockIdx.x;
    const int tid = threadIdx.x;
    if (bid >= 256) {  // ---- copy w -> out+4097 (dst 4B-aligned only) ----
        const int cid = bid - 256;  // 0..63, each block: 16384 float4s
        const float4* wsrc = (const float4*)w;
#pragma unroll 4
        for (int p = 0; p < 32; ++p) {
            const size_t f4i = (size_t)cid * 16384 + tid + 512 * p;
            float4 v = wsrc[f4i];
            float* dst = outcpy + 4 * f4i;
            dst[0] = v.x; dst[1] = v.y; dst[2] = v.z; dst[3] = v.w;
        }
        return;
    }
    const int lane = tid & 63;
    const int wv = tid >> 6;            // 0..7
    const int lrow = lane & 15;
    const int lk8 = (lane >> 4) * 8;
    const int crow4 = (lane >> 4) * 4;
    if (bid < 128) {  // ---- gram: full 128x128 output, mat = bid ----
        __shared__ float sA[8], sB[8];
        const int mat = bid;
        const float* src = (mat < Bn) ? (x + (size_t)mat * Dn) : (w + (size_t)(mat - Bn) * Dn);
        unsigned short (*hi)[72] = (unsigned short(*)[72])smem;
        unsigned short (*lo)[72] = (unsigned short(*)[72])(smem + 18432);
        f32x4 acc[8] = {};
        float ssq = 0.f;
        float4 cur[4], nxt[4];
#pragma unroll
        for (int p = 0; p < 4; ++p) {
            const int f = tid + 512 * p;            // 0..2047
            cur[p] = *(const float4*)(src + (size_t)(f >> 4) * Hn + (f & 15) * 4);
        }
        for (int c = 0; c < 8; ++c) {
#pragma unroll
            for (int p = 0; p < 4; ++p) {
                const int f = tid + 512 * p;
                const int r = f >> 4, c4 = (f & 15) * 4;
                float4 v = cur[p];
                ssq += v.x * v.x + v.y * v.y + v.z * v.z + v.w * v.w;
                unsigned short h0 = f2bf(v.x), h1 = f2bf(v.y), h2 = f2bf(v.z), h3 = f2bf(v.w);
                *(ushort4*)&hi[r][c4] = make_ushort4(h0, h1, h2, h3);
                *(ushort4*)&lo[r][c4] = make_ushort4(f2bf(v.x - bf2f(h0)), f2bf(v.y - bf2f(h1)),
                                                     f2bf(v.z - bf2f(h2)), f2bf(v.w - bf2f(h3)));
            }
            if (c < 7) {
#pragma unroll
                for (int p = 0; p < 4; ++p) {
                    const int f = tid + 512 * p;
                    nxt[p] = *(const float4*)(src + (size_t)(f >> 4) * Hn + (c + 1) * 64 + (f & 15) * 4);
                }
            }
            __syncthreads();
#pragma unroll
            for (int ks = 0; ks < 64; ks += 32) {
                const int arow = wv * 16 + lrow;
                bf16x8 ah = *(const bf16x8*)&hi[arow][ks + lk8];
                bf16x8 al = *(const bf16x8*)&lo[arow][ks + lk8];
#pragma unroll
                for (int j = 0; j < 8; ++j) {
                    const int brow = j * 16 + lrow;
                    bf16x8 bh = *(const bf16x8*)&hi[brow][ks + lk8];
                    bf16x8 bl = *(const bf16x8*)&lo[brow][ks + lk8];
                    acc[j] = __builtin_amdgcn_mfma_f32_16x16x32_bf16(ah, bh, acc[j], 0, 0, 0);
                    acc[j] = __builtin_amdgcn_mfma_f32_16x16x32_bf16(ah, bl, acc[j], 0, 0, 0);
                    acc[j] = __builtin_amdgcn_mfma_f32_16x16x32_bf16(al, bh, acc[j], 0, 0, 0);
                }
            }
            __syncthreads();
            if (c < 7) {
#pragma unroll
                for (int p = 0; p < 4; ++p) cur[p] = nxt[p];
            }
        }
        // store fp32 G, permuted: pos = wv*2048 + j*256 + lane*4 + r (coalesced 1KB/instr)
        float* dst = gF + (size_t)mat * SSn + wv * 2048;
        float sq = 0.f;
#pragma unroll
        for (int j = 0; j < 8; ++j) {
            f32x4 v = acc[j];
            sq += v[0] * v[0] + v[1] * v[1] + v[2] * v[2] + v[3] * v[3];
            *(f32x4*)(dst + j * 256 + lane * 4) = v;
        }
        // row sums (true rows): row = wv*16 + crow4 + r
#pragma unroll
        for (int r = 0; r < 4; ++r) {
            float rs = 0.f;
#pragma unroll
            for (int j = 0; j < 8; ++j) rs += acc[j][r];
            rs += __shfl_xor(rs, 1, 64);
            rs += __shfl_xor(rs, 2, 64);
            rs += __shfl_xor(rs, 4, 64);
            rs += __shfl_xor(rs, 8, 64);
            if (lrow == 0) rsT[(size_t)(wv * 16 + crow4 + r) * 128 + mat] = rs;
        }
        sq = wredf(sq);
        ssq = wredf(ssq);
        if (lane == 0) { sA[wv] = sq; sB[wv] = ssq; }
        __syncthreads();
        if (tid == 0) {
            float g2 = 0.f, tr = 0.f;
#pragma unroll
            for (int i = 0; i < 8; ++i) { g2 += sA[i]; tr += sB[i]; }
            hpartG[mat] = g2;
            if (mat < Bn) x2[mat] = tr; else w2[mat - Bn] = tr;
        }
    } else {  // ---- dist dots: bf16-hi MFMA, K-slice 512/block ----
        const int did = bid - 128;  // 0..127
        unsigned short (*la)[264] = (unsigned short(*)[264])smem;
        unsigned short (*lb)[264] = (unsigned short(*)[264])(smem + 33792);
        const int rg = wv >> 1, cgb = (wv & 1) * 2;
        f32x4 acc[2] = {};
        for (int cc = 0; cc < 2; ++cc) {
            const int k0 = did * 512 + cc * 256;
            __syncthreads();
#pragma unroll
            for (int p = 0; p < 8; ++p) {
                const int f = tid + 512 * p;   // 0..4095 = 64 rows x 64 f4
                const int row = f >> 6, c4 = (f & 63) * 4;
                float4 vx = *(const float4*)(x + (size_t)row * Dn + k0 + c4);
                float4 vw = *(const float4*)(w + (size_t)row * Dn + k0 + c4);
                *(ushort4*)&la[row][c4] = make_ushort4(f2bf(vx.x), f2bf(vx.y), f2bf(vx.z), f2bf(vx.w));
                *(ushort4*)&lb[row][c4] = make_ushort4(f2bf(vw.x), f2bf(vw.y), f2bf(vw.z), f2bf(vw.w));
            }
            __syncthreads();
#pragma unroll
            for (int ks = 0; ks < 8; ++ks) {
                bf16x8 a = *(const bf16x8*)&la[rg * 16 + lrow][ks * 32 + lk8];
#pragma unroll
                for (int q = 0; q < 2; ++q) {
                    bf16x8 b = *(const bf16x8*)&lb[(cgb + q) * 16 + lrow][ks * 32 + lk8];
                    acc[q] = __builtin_amdgcn_mfma_f32_16x16x32_bf16(a, b, acc[q], 0, 0, 0);
                }
            }
        }
        float* p = partials + (size_t)did * 4096;
#pragma unroll
        for (int q = 0; q < 2; ++q)
#pragma unroll
            for (int r = 0; r < 4; ++r)
                p[(rg * 16 + crow4 + r) * 64 + (cgb + q) * 16 + lrow] = acc[q][r];
    }
}

// ===== Kernel B: fp32 hxy-dots (bid<256) | dist-reduce (256..319) | sumS (320)
__global__ __launch_bounds__(256) void kB(const float* __restrict__ gF,
                                          const float* __restrict__ partials,
                                          const float* __restrict__ rsT,
                                          const float* __restrict__ hpartG,
                                          const float* __restrict__ x2,
                                          const float* __restrict__ w2,
                                          float* __restrict__ partials2,
                                          float* __restrict__ Sv,
                                          float* __restrict__ hxx,
                                          float* __restrict__ hyy,
                                          float* __restrict__ od) {
    __shared__ __align__(16) unsigned char smem[65536];
    const int bid = blockIdx.x;
    const int tid = threadIdx.x;
    if (bid < 256) {  // ---- fp32 dots over permuted G, K-slice 64 ----
        float (*la)[68] = (float(*)[68])smem;
        float (*lb)[68] = (float(*)[68])(smem + 17408);
        const int k0 = bid * 64;
        const int slc = (tid & 15) * 4;
        for (int r = tid >> 4; r < 64; r += 16) {
            *(float4*)&la[r][slc] = *(const float4*)(gF + (size_t)r * SSn + k0 + slc);
            *(float4*)&lb[r][slc] = *(const float4*)(gF + (size_t)(64 + r) * SSn + k0 + slc);
        }
        __syncthreads();
        const int ry = tid >> 4, tx = tid & 15;
        float acc[4][4] = {};
        for (int k = 0; k < 64; k += 4) {
            float4 av[4], bv[4];
#pragma unroll
            for (int i = 0; i < 4; ++i) av[i] = *(const float4*)&la[4 * ry + i][k];
#pragma unroll
            for (int j = 0; j < 4; ++j) bv[j] = *(const float4*)&lb[16 * j + tx][k];
#pragma unroll
            for (int i = 0; i < 4; ++i)
#pragma unroll
                for (int j = 0; j < 4; ++j)
                    acc[i][j] += av[i].x * bv[j].x + av[i].y * bv[j].y +
                                 av[i].z * bv[j].z + av[i].w * bv[j].w;
        }
        float* p = partials2 + (size_t)bid * 4096;
#pragma unroll
        for (int i = 0; i < 4; ++i)
#pragma unroll
            for (int j = 0; j < 4; ++j)
                p[(4 * ry + i) * 64 + 16 * j + tx] = acc[i][j];
    } else if (bid < 320) {  // ---- dist reduce (P=128) ----
        double* red = (double*)smem;
        const int b2 = bid - 256;
        const int o = tid & 63, sl = tid >> 6;
        const int i = b2 * 64 + o;
        double s = 0;
        for (int t = 0; t < 32; ++t)
            s += (double)partials[(size_t)(sl + 4 * t) * 4096 + i];
        red[sl * 64 + o] = s;
        __syncthreads();
        if (tid < 64) {
            double t = red[tid] + red[64 + tid] + red[128 + tid] + red[192 + tid];
            float d2 = x2[b2] + w2[tid] - 2.f * (float)t;
            od[b2 * 64 + tid] = sqrtf(fmaxf(d2, 0.f));
        }
    } else {  // ---- sumS: LDS-staged rsT; S, hxx, hyy ----
        float* rl = (float*)smem;  // 128*128 floats
        for (int p = 0; p < 16; ++p) {
            const int f4 = tid + 256 * p;
            *(float4*)(rl + 4 * f4) = *(const float4*)(rsT + 4 * f4);
        }
        __syncthreads();
        if (tid < 128) {
            float s = 0.f, q = 0.f;
            for (int t = 0; t < 128; ++t) {
                float v = rl[t * 128 + tid];
                s += v; q += v * v;
            }
            Sv[tid] = s;
            double val = (double)hpartG[tid] - (double)q * (1.0 / 64.0)
                       + (double)s * (double)s * (1.0 / 16384.0);
            if (tid < 64) hxx[tid] = (float)val; else hyy[tid - 64] = (float)val;
        }
    }
}

// ===== Kernel C: hxy reduce + centering corrections (grid 64 x 256) ========
__global__ __launch_bounds__(256) void kC(const float* __restrict__ partials2,
                                          const float* __restrict__ rsT,
                                          const float* __restrict__ Sv,
                                          double* __restrict__ hxy) {
    __shared__ double red[256];
    const int b = blockIdx.x;
    const int o = threadIdx.x & 63;
    const int sl = threadIdx.x >> 6;
    const int i = b * 64 + o;
    double s0 = 0, s1 = 0;
    for (int t = 0; t < 64; t += 2) {
        s0 += (double)partials2[(size_t)(sl + 4 * t) * 4096 + i];
        s1 += (double)partials2[(size_t)(sl + 4 * (t + 1)) * 4096 + i];
    }
    double corr = 0;
    for (int t = 0; t < 32; ++t) {
        const int ss = sl * 32 + t;
        corr += (double)rsT[ss * 128 + b] * (double)rsT[ss * 128 + 64 + o];
    }
    red[sl * 64 + o] = (s0 + s1) - corr * (1.0 / 64.0);
    __syncthreads();
    if (threadIdx.x < 64) {
        double t = red[threadIdx.x] + red[64 + threadIdx.x] +
                   red[128 + threadIdx.x] + red[192 + threadIdx.x];
        t += (double)Sv[b] * (double)Sv[64 + threadIdx.x] * (1.0 / 16384.0);
        hxy[b * 64 + threadIdx.x] = t;
    }
}

// ===== Kernel D: parallel argmin (== argmax of -log(r+eps), first-wins) ====
__global__ void finalize_k(const double* __restrict__ hxy, const float* __restrict__ hxx,
                           const float* __restrict__ hyy, float* __restrict__ out0,
                           float* __restrict__ oidx) {
    __shared__ double inv_sx[64], inv_sy[64];
    __shared__ double qv[256];
    __shared__ int qi[256];
    __shared__ int sidx[64];
    __shared__ double sred[4];
    const int tid = threadIdx.x;  // 256
    if (tid < 64) {
        inv_sx[tid] = 1.0 / sqrt((double)hxx[tid]);
        inv_sy[tid] = 1.0 / sqrt((double)hyy[tid]);
    }
    __syncthreads();
    {   // 4 threads per row b, 16 candidates each
        const int b = tid >> 2, q = tid & 3;
        double best = 1e300; int bi = 64;
        for (int c = q * 16; c < q * 16 + 16; ++c) {
            double v = fabs(hxy[b * 64 + c]) * inv_sy[c];
            if (v < best) { best = v; bi = c; }
        }
        qv[tid] = best; qi[tid] = bi;
    }
    __syncthreads();
    if (tid < 64) {
        double best = qv[4 * tid]; int bi = qi[4 * tid];
        for (int q = 1; q < 4; ++q) {
            if (qv[4 * tid + q] < best) { best = qv[4 * tid + q]; bi = qi[4 * tid + q]; }
        }
        sidx[tid] = bi;
        oidx[tid] = (float)bi;
    }
    __syncthreads();
    double s = 0.0;
    for (int e = tid; e < 4096; e += 256) {
        const int b = e >> 6, c = e & 63;
        const int ic = sidx[c];
        s += fabs(hxy[b * 64 + ic]) * inv_sx[b] * inv_sy[ic];
    }
#pragma unroll
    for (int o = 32; o > 0; o >>= 1) s += __shfl_down(s, o, 64);
    if ((tid & 63) == 0) sred[tid >> 6] = s;
    __syncthreads();
    if (tid == 0) {
        double t = sred[0] + sred[1] + sred[2] + sred[3];
        out0[0] = (float)(-log(t / 4096.0 + 1e-8));
    }
}

extern "C" void kernel_launch(void* const* d_in, const int* in_sizes, int n_in,
                              void* d_out, int out_size, void* d_ws, size_t ws_size,
                              hipStream_t stream) {
    const float* x = (const float*)d_in[0];   // (64, 65536)
    const float* w = (const float*)d_in[1];   // (64, 65536)
    float* out = (float*)d_out;
    // out: [0]=loss, [1..4096]=dist, [4097..4198400]=centroid copy, [4198401..]=idx
    float* ws = (float*)d_ws;
    float* gF        = ws;                        // 128*16384 fp32 (permuted grams)
    float* partials  = ws + 2097152;              // 128*4096
    float* partials2 = ws + 2621440;              // 256*4096
    float* rsT       = ws + 3670016;              // 128*128 [s][mat]
    float* hpartG    = ws + 3686400;              // 128
    float* Sv        = ws + 3686528;              // 128
    float* x2        = ws + 3686656;              // 64
    float* w2        = ws + 3686720;              // 64
    float* hxx       = ws + 3686784;              // 64
    float* hyy       = ws + 3686848;              // 64
    double* hxyD     = (double*)(ws + 3686912);   // 4096 doubles (8B aligned)

    kA<<<320, 512, 0, stream>>>(x, w, gF, rsT, hpartG, x2, w2, partials, out + 4097);
    kB<<<321, 256, 0, stream>>>(gF, partials, rsT, hpartG, x2, w2,
                                partials2, Sv, hxx, hyy, out + 1);
    kC<<<64, 256, 0, stream>>>(partials2, rsT, Sv, hxyD);
    finalize_k<<<1, 256, 0, stream>>>(hxyD, hxx, hyy, out, out + 4198401);
}